// Round 5
// baseline (12281.161 us; speedup 1.0000x reference)
//
#include <hip/hip_runtime.h>
#include <cstddef>

#define NB 32      // batch
#define NP 196     // pixels
#define NE 2048    // encoder dim
#define ND 512     // decoder/att/emb dim
#define NV 32000   // vocab
#define NL 21
#define NT 20      // decode steps

// ---------------- software grid barrier (sense reversal, device scope) ----------------
__device__ __forceinline__ void gbar(unsigned* cnt, unsigned* sns, unsigned want)
{
    __syncthreads();
    if (threadIdx.x == 0) {
        __builtin_amdgcn_fence(__ATOMIC_SEQ_CST, "agent");   // release: flush this block's writes
        unsigned prev = __hip_atomic_fetch_add(cnt, 1u, __ATOMIC_ACQ_REL, __HIP_MEMORY_SCOPE_AGENT);
        if (prev == 255u) {
            __hip_atomic_store(cnt, 0u, __ATOMIC_RELAXED, __HIP_MEMORY_SCOPE_AGENT);
            __hip_atomic_store(sns, want, __ATOMIC_RELEASE, __HIP_MEMORY_SCOPE_AGENT);
        } else {
            unsigned iters = 0;
            while (__hip_atomic_load(sns, __ATOMIC_ACQUIRE, __HIP_MEMORY_SCOPE_AGENT) != want) {
                __builtin_amdgcn_s_sleep(2);
                if (++iters > 400000000u) break;             // failsafe, never hit when co-resident
            }
        }
        __builtin_amdgcn_fence(__ATOMIC_ACQUIRE, "agent");   // acquire: invalidate caches
    }
    __syncthreads();
}

// ---------------- setup ----------------

// stable descending argsort + live-row map + barrier-state init
__global__ void k_sort(const int* __restrict__ lens, int* __restrict__ sind, int* __restrict__ dlens,
                       int* __restrict__ rowmap, int* __restrict__ mpad, unsigned* __restrict__ barst)
{
    int i = threadIdx.x;
    if (i < NB) {
        int li = lens[i];
        int r = 0;
        for (int j = 0; j < NB; ++j) {
            int lj = lens[j];
            if (lj > li || (lj == li && j < i)) ++r;
        }
        sind[r] = i;
        dlens[r] = li - 1;
    }
    __syncthreads();
    if (i == 0) {
        int cnt = 0;
        for (int t = 0; t < NT; ++t)
            for (int b = 0; b < NB; ++b)
                if (t < dlens[b]) rowmap[cnt++] = t * NB + b;
        int pad = (cnt + 63) & ~63;
        for (int r = cnt; r < pad; ++r) rowmap[r] = -1;
        mpad[0] = pad;
        barst[0] = 0u;   // count
        barst[1] = 0u;   // sense
    }
}

__global__ __launch_bounds__(256) void k_mean(const float* __restrict__ enc, const int* __restrict__ sind,
                                              float* __restrict__ mean_enc)
{
    int b = blockIdx.y;
    int k = blockIdx.x * 256 + threadIdx.x;
    const float* e = enc + (size_t)sind[b] * NP * NE + k;
    float s0 = 0.f, s1 = 0.f, s2 = 0.f, s3 = 0.f;
    for (int p = 0; p < NP; p += 4) {
        s0 += e[(size_t)(p + 0) * NE];
        s1 += e[(size_t)(p + 1) * NE];
        s2 += e[(size_t)(p + 2) * NE];
        s3 += e[(size_t)(p + 3) * NE];
    }
    mean_enc[(size_t)b * NE + k] = (s0 + s1 + s2 + s3) * (1.0f / NP);
}

// zero-fill dead prediction rows
__global__ __launch_bounds__(256) void k_zero(const int* __restrict__ dlens, float* __restrict__ out)
{
    int b = blockIdx.x / NT, t = blockIdx.x % NT;
    if (t < dlens[b]) return;
    float4 z = {0.f, 0.f, 0.f, 0.f};
    float4* row = (float4*)(out + ((size_t)b * NT + t) * NV);
    for (int i = threadIdx.x; i < NV / 4; i += 256) row[i] = z;
}

// ---------------- skinny GEMM (h0/c0; also seeds xh h-part) ----------------
__global__ __launch_bounds__(256) void gemm_skinny(
    const float* __restrict__ A0, const float* __restrict__ W0a, const float* __restrict__ W0b,
    const float* __restrict__ ba, const float* __restrict__ bb,
    float* __restrict__ C, float* __restrict__ xh)
{
    __shared__ float As[32][32];
    __shared__ float Ws[64][33];
    int n0 = blockIdx.x * 64;
    int tid = threadIdx.x;
    int lb = tid / 8, lkq = tid % 8;
    int b4 = (tid / 32) * 4, nl = (tid % 32) * 2;
    float acc[4][2] = {};
    for (int kt = 0; kt < NE; kt += 32) {
        float4 a4 = *reinterpret_cast<const float4*>(A0 + (size_t)lb * NE + kt + lkq * 4);
        As[lkq * 4 + 0][lb] = a4.x; As[lkq * 4 + 1][lb] = a4.y;
        As[lkq * 4 + 2][lb] = a4.z; As[lkq * 4 + 3][lb] = a4.w;
        #pragma unroll
        for (int r = 0; r < 2; ++r) {
            int s = tid + r * 256;
            int n_l = s / 8, kq = s % 8;
            int ng = n0 + n_l;
            const float* wrow = (ng < 512) ? (W0a + (size_t)ng * NE)
                                           : (W0b + (size_t)(ng - 512) * NE);
            float4 w4 = *reinterpret_cast<const float4*>(wrow + kt + kq * 4);
            Ws[n_l][kq * 4 + 0] = w4.x; Ws[n_l][kq * 4 + 1] = w4.y;
            Ws[n_l][kq * 4 + 2] = w4.z; Ws[n_l][kq * 4 + 3] = w4.w;
        }
        __syncthreads();
        #pragma unroll
        for (int k = 0; k < 32; ++k) {
            float4 av = *reinterpret_cast<const float4*>(&As[k][b4]);
            float w0 = Ws[nl][k], w1 = Ws[nl + 1][k];
            acc[0][0] += av.x * w0; acc[0][1] += av.x * w1;
            acc[1][0] += av.y * w0; acc[1][1] += av.y * w1;
            acc[2][0] += av.z * w0; acc[2][1] += av.z * w1;
            acc[3][0] += av.w * w0; acc[3][1] += av.w * w1;
        }
        __syncthreads();
    }
    #pragma unroll
    for (int j = 0; j < 2; ++j) {
        int ng = n0 + nl + j;
        float bias = (ng < 512) ? ba[ng] : bb[ng - 512];
        #pragma unroll
        for (int i = 0; i < 4; ++i) {
            float v = acc[i][j] + bias;
            int b = b4 + i;
            C[(size_t)b * 1024 + ng] = v;
            if (ng < 512) xh[(size_t)b * 3072 + 2560 + ng] = v;   // seed h into xh
        }
    }
}

// ---------------- att1 GEMM: BM=128 BN=64, 8x4/thread ----------------
__global__ __launch_bounds__(256) void gemm_att1(
    const float* __restrict__ A, const float* __restrict__ W, const float* __restrict__ bias,
    float* __restrict__ C, const int* __restrict__ sind)
{
    __shared__ float As[16][128];
    __shared__ float Ws[16][64];
    int bn0 = blockIdx.x * 64, bm0 = blockIdx.y * 128;
    int tid = threadIdx.x;
    int ty = tid / 16, tx = tid % 16;
    int lm = tid / 4, lk = (tid % 4) * 4;
    int mg0 = bm0 + lm, mg1 = bm0 + 64 + lm;
    const float* arow0 = A + ((size_t)sind[mg0 / NP] * NP + mg0 % NP) * NE;
    const float* arow1 = A + ((size_t)sind[mg1 / NP] * NP + mg1 % NP) * NE;
    const float* wrow = W + (size_t)(bn0 + lm) * NE;
    float4 bias4 = *reinterpret_cast<const float4*>(bias + bn0 + tx * 4);
    float acc[8][4] = {};
    for (int kt = 0; kt < NE; kt += 16) {
        float4 a0 = *reinterpret_cast<const float4*>(arow0 + kt + lk);
        float4 a1 = *reinterpret_cast<const float4*>(arow1 + kt + lk);
        float4 w4 = *reinterpret_cast<const float4*>(wrow + kt + lk);
        As[lk + 0][lm] = a0.x; As[lk + 1][lm] = a0.y; As[lk + 2][lm] = a0.z; As[lk + 3][lm] = a0.w;
        As[lk + 0][64 + lm] = a1.x; As[lk + 1][64 + lm] = a1.y; As[lk + 2][64 + lm] = a1.z; As[lk + 3][64 + lm] = a1.w;
        Ws[lk + 0][lm] = w4.x; Ws[lk + 1][lm] = w4.y; Ws[lk + 2][lm] = w4.z; Ws[lk + 3][lm] = w4.w;
        __syncthreads();
        #pragma unroll
        for (int k = 0; k < 16; ++k) {
            float4 av0 = *reinterpret_cast<const float4*>(&As[k][ty * 8]);
            float4 av1 = *reinterpret_cast<const float4*>(&As[k][ty * 8 + 4]);
            float4 wv = *reinterpret_cast<const float4*>(&Ws[k][tx * 4]);
            acc[0][0] += av0.x * wv.x; acc[0][1] += av0.x * wv.y; acc[0][2] += av0.x * wv.z; acc[0][3] += av0.x * wv.w;
            acc[1][0] += av0.y * wv.x; acc[1][1] += av0.y * wv.y; acc[1][2] += av0.y * wv.z; acc[1][3] += av0.y * wv.w;
            acc[2][0] += av0.z * wv.x; acc[2][1] += av0.z * wv.y; acc[2][2] += av0.z * wv.z; acc[2][3] += av0.z * wv.w;
            acc[3][0] += av0.w * wv.x; acc[3][1] += av0.w * wv.y; acc[3][2] += av0.w * wv.z; acc[3][3] += av0.w * wv.w;
            acc[4][0] += av1.x * wv.x; acc[4][1] += av1.x * wv.y; acc[4][2] += av1.x * wv.z; acc[4][3] += av1.x * wv.w;
            acc[5][0] += av1.y * wv.x; acc[5][1] += av1.y * wv.y; acc[5][2] += av1.y * wv.z; acc[5][3] += av1.y * wv.w;
            acc[6][0] += av1.z * wv.x; acc[6][1] += av1.z * wv.y; acc[6][2] += av1.z * wv.z; acc[6][3] += av1.z * wv.w;
            acc[7][0] += av1.w * wv.x; acc[7][1] += av1.w * wv.y; acc[7][2] += av1.w * wv.z; acc[7][3] += av1.w * wv.w;
        }
        __syncthreads();
    }
    #pragma unroll
    for (int i = 0; i < 8; ++i) {
        int m = bm0 + ty * 8 + i;
        float4 o;
        o.x = acc[i][0] + bias4.x; o.y = acc[i][1] + bias4.y;
        o.z = acc[i][2] + bias4.z; o.w = acc[i][3] + bias4.w;
        *reinterpret_cast<float4*>(C + (size_t)m * ND + bn0 + tx * 4) = o;
    }
}

// ---------------- preds GEMM: BM=64 BN=128, 8x4/thread, live rows only ----------------
__global__ __launch_bounds__(256) void gemm_preds(
    const float* __restrict__ A, const float* __restrict__ W, const float* __restrict__ bias,
    float* __restrict__ C, const int* __restrict__ rowmap, const int* __restrict__ mpad)
{
    int bm0 = blockIdx.x * 64;
    if (bm0 >= mpad[0]) return;
    int bn0 = blockIdx.y * 128;
    __shared__ float As[16][64];
    __shared__ float Ws[16][128];
    int tid = threadIdx.x;
    int ty = tid / 32, tx = tid % 32;
    int lm = tid / 4, lk = (tid % 4) * 4;
    int rid = rowmap[bm0 + lm];
    const float* arow = A + (size_t)(rid < 0 ? 0 : rid) * ND;
    const float* wrow0 = W + (size_t)(bn0 + lm) * ND;
    const float* wrow1 = W + (size_t)(bn0 + 64 + lm) * ND;
    float4 bias4 = *reinterpret_cast<const float4*>(bias + bn0 + tx * 4);
    float acc[8][4] = {};
    for (int kt = 0; kt < ND; kt += 16) {
        float4 a4 = *reinterpret_cast<const float4*>(arow + kt + lk);
        float4 w0 = *reinterpret_cast<const float4*>(wrow0 + kt + lk);
        float4 w1 = *reinterpret_cast<const float4*>(wrow1 + kt + lk);
        As[lk + 0][lm] = a4.x; As[lk + 1][lm] = a4.y; As[lk + 2][lm] = a4.z; As[lk + 3][lm] = a4.w;
        Ws[lk + 0][lm] = w0.x; Ws[lk + 1][lm] = w0.y; Ws[lk + 2][lm] = w0.z; Ws[lk + 3][lm] = w0.w;
        Ws[lk + 0][64 + lm] = w1.x; Ws[lk + 1][64 + lm] = w1.y; Ws[lk + 2][64 + lm] = w1.z; Ws[lk + 3][64 + lm] = w1.w;
        __syncthreads();
        #pragma unroll
        for (int k = 0; k < 16; ++k) {
            float4 av0 = *reinterpret_cast<const float4*>(&As[k][ty * 8]);
            float4 av1 = *reinterpret_cast<const float4*>(&As[k][ty * 8 + 4]);
            float4 wv = *reinterpret_cast<const float4*>(&Ws[k][tx * 4]);
            acc[0][0] += av0.x * wv.x; acc[0][1] += av0.x * wv.y; acc[0][2] += av0.x * wv.z; acc[0][3] += av0.x * wv.w;
            acc[1][0] += av0.y * wv.x; acc[1][1] += av0.y * wv.y; acc[1][2] += av0.y * wv.z; acc[1][3] += av0.y * wv.w;
            acc[2][0] += av0.z * wv.x; acc[2][1] += av0.z * wv.y; acc[2][2] += av0.z * wv.z; acc[2][3] += av0.z * wv.w;
            acc[3][0] += av0.w * wv.x; acc[3][1] += av0.w * wv.y; acc[3][2] += av0.w * wv.z; acc[3][3] += av0.w * wv.w;
            acc[4][0] += av1.x * wv.x; acc[4][1] += av1.x * wv.y; acc[4][2] += av1.x * wv.z; acc[4][3] += av1.x * wv.w;
            acc[5][0] += av1.y * wv.x; acc[5][1] += av1.y * wv.y; acc[5][2] += av1.y * wv.z; acc[5][3] += av1.y * wv.w;
            acc[6][0] += av1.z * wv.x; acc[6][1] += av1.z * wv.y; acc[6][2] += av1.z * wv.z; acc[6][3] += av1.z * wv.w;
            acc[7][0] += av1.w * wv.x; acc[7][1] += av1.w * wv.y; acc[7][2] += av1.w * wv.z; acc[7][3] += av1.w * wv.w;
        }
        __syncthreads();
    }
    #pragma unroll
    for (int i = 0; i < 8; ++i) {
        int rm = rowmap[bm0 + ty * 8 + i];
        if (rm < 0) continue;
        int t = rm / NB, b = rm % NB;
        float4 o;
        o.x = acc[i][0] + bias4.x; o.y = acc[i][1] + bias4.y;
        o.z = acc[i][2] + bias4.z; o.w = acc[i][3] + bias4.w;
        *reinterpret_cast<float4*>(C + ((size_t)b * NT + t) * NV + bn0 + tx * 4) = o;
    }
}

// ---------------- persistent time-loop kernel (256 blocks x 256, software barrier) ----------------
__global__ __launch_bounds__(256) void k_loop(
    const float* __restrict__ enc, const int* __restrict__ sind, const int* __restrict__ dlens,
    const int* __restrict__ caps, const float* __restrict__ emb_W,
    const float* __restrict__ att1,
    const float* __restrict__ w_fa, const float* __restrict__ b_fa,
    const float* __restrict__ W_da, const float* __restrict__ b_da,
    const float* __restrict__ W_fb, const float* __restrict__ b_fb,
    const float* __restrict__ W_ih, const float* __restrict__ b_ih,
    const float* __restrict__ W_hh, const float* __restrict__ b_hh,
    float* __restrict__ hc, float* __restrict__ e,
    float* __restrict__ xh, float* __restrict__ gatep,
    float* __restrict__ gpart, float* __restrict__ hseq,
    float* __restrict__ out_alpha, unsigned* __restrict__ barst)
{
    int blk = blockIdx.x, tid = threadIdx.x;
    __shared__ float smem[3200];
    unsigned* cnt = barst;
    unsigned* sns = barst + 1;
    unsigned sense = 0;

    for (int t = 0; t < NT; ++t) {
        // ===== Phase B: gate partials (32 ntiles x 8 ks); ks==7 blocks also att2+e
        {
            int nt = blk & 31, ks = blk >> 5;
            float* As = smem;                                   // [32*32]
            float (*Ws)[33] = (float(*)[33])(smem + 1024);      // [64][33]
            int n0 = nt * 64;
            int lb = tid / 8, lkq = tid % 8;
            int b4 = (tid / 32) * 4, nl = (tid % 32) * 2;
            float acc[4][2] = {};
            for (int kt = ks * 64; kt < ks * 64 + 64; kt += 32) {
                float4 a4 = *reinterpret_cast<const float4*>(hc + (size_t)lb * 1024 + kt + lkq * 4);
                As[(lkq * 4 + 0) * 32 + lb] = a4.x; As[(lkq * 4 + 1) * 32 + lb] = a4.y;
                As[(lkq * 4 + 2) * 32 + lb] = a4.z; As[(lkq * 4 + 3) * 32 + lb] = a4.w;
                #pragma unroll
                for (int r = 0; r < 2; ++r) {
                    int s = tid + r * 256;
                    int n_l = s / 8, kq = s % 8;
                    float4 w4 = *reinterpret_cast<const float4*>(W_fb + (size_t)(n0 + n_l) * ND + kt + kq * 4);
                    Ws[n_l][kq * 4 + 0] = w4.x; Ws[n_l][kq * 4 + 1] = w4.y;
                    Ws[n_l][kq * 4 + 2] = w4.z; Ws[n_l][kq * 4 + 3] = w4.w;
                }
                __syncthreads();
                #pragma unroll
                for (int k = 0; k < 32; ++k) {
                    float4 av = *reinterpret_cast<const float4*>(&As[k * 32 + b4]);
                    float w0 = Ws[nl][k], w1 = Ws[nl + 1][k];
                    acc[0][0] += av.x * w0; acc[0][1] += av.x * w1;
                    acc[1][0] += av.y * w0; acc[1][1] += av.y * w1;
                    acc[2][0] += av.z * w0; acc[2][1] += av.z * w1;
                    acc[3][0] += av.w * w0; acc[3][1] += av.w * w1;
                }
                __syncthreads();
            }
            float* Cp = gatep + (size_t)ks * NB * 2048;
            #pragma unroll
            for (int j = 0; j < 2; ++j)
                #pragma unroll
                for (int i = 0; i < 4; ++i)
                    Cp[(size_t)(b4 + i) * 2048 + n0 + nl + j] = acc[i][j];

            if (ks == 7) {
                int b = nt;
                __syncthreads();
                // smem: [0..511]=att2, [512..1023]=w_fa, [1024..1535]=h
                smem[512 + tid] = w_fa[tid]; smem[768 + tid] = w_fa[256 + tid];
                smem[1024 + tid] = hc[b * 1024 + tid]; smem[1280 + tid] = hc[b * 1024 + 256 + tid];
                __syncthreads();
                int w = tid >> 6, lane = tid & 63;
                const float* hh = &smem[1024];
                for (int r = 0; r < 128; ++r) {
                    int row = w * 128 + r;
                    const float* wr = W_da + (size_t)row * ND + lane * 8;
                    float4 wa = *reinterpret_cast<const float4*>(wr);
                    float4 wb = *reinterpret_cast<const float4*>(wr + 4);
                    float4 h0 = *reinterpret_cast<const float4*>(hh + lane * 8);
                    float4 h1 = *reinterpret_cast<const float4*>(hh + lane * 8 + 4);
                    float s = wa.x * h0.x + wa.y * h0.y + wa.z * h0.z + wa.w * h0.w
                            + wb.x * h1.x + wb.y * h1.y + wb.z * h1.z + wb.w * h1.w;
                    for (int off = 32; off > 0; off >>= 1) s += __shfl_down(s, off);
                    if (lane == 0) smem[row] = s + b_da[row];
                }
                __syncthreads();
                float bfa = b_fa[0];
                const float* a1 = att1 + (size_t)b * NP * ND;
                for (int i = 0; i < 49; ++i) {
                    int p = w + 4 * i;
                    const float* row = a1 + (size_t)p * ND;
                    float s = 0.f;
                    #pragma unroll
                    for (int j = 0; j < 2; ++j) {
                        int d = j * 256 + lane * 4;
                        float4 v = *reinterpret_cast<const float4*>(row + d);
                        float4 a2 = *reinterpret_cast<const float4*>(&smem[d]);
                        float4 wf = *reinterpret_cast<const float4*>(&smem[512 + d]);
                        s += fmaxf(v.x + a2.x, 0.f) * wf.x + fmaxf(v.y + a2.y, 0.f) * wf.y
                           + fmaxf(v.z + a2.z, 0.f) * wf.z + fmaxf(v.w + a2.w, 0.f) * wf.w;
                    }
                    for (int off = 32; off > 0; off >>= 1) s += __shfl_down(s, off);
                    if (lane == 0) e[b * NP + p] = s + bfa;
                }
            }
        }
        sense ^= 1; gbar(cnt, sns, sense);

        // ===== Phase C: softmax + awe + gate + x  (32 b x 8 kchunks of 256)
        {
            int b = blk >> 3, kc = blk & 7;
            float* red = smem + 256;
            float m = -1e30f;
            if (tid < NP) { float v = e[b * NP + tid]; smem[tid] = v; m = v; }
            red[tid] = m; __syncthreads();
            for (int s2 = 128; s2 > 0; s2 >>= 1) { if (tid < s2) red[tid] = fmaxf(red[tid], red[tid + s2]); __syncthreads(); }
            m = red[0]; __syncthreads();
            float sm = 0.f;
            if (tid < NP) { float v = expf(smem[tid] - m); smem[tid] = v; sm = v; }
            red[tid] = sm; __syncthreads();
            for (int s2 = 128; s2 > 0; s2 >>= 1) { if (tid < s2) red[tid] += red[tid + s2]; __syncthreads(); }
            float inv = 1.0f / red[0]; __syncthreads();
            if (tid < NP) smem[tid] *= inv;
            __syncthreads();

            int k = kc * 256 + tid;
            const float* eb = enc + (size_t)sind[b] * NP * NE + k;
            float s0 = 0.f, s1 = 0.f, s2v = 0.f, s3 = 0.f;
            for (int p = 0; p < 196; p += 4) {
                s0 += smem[p + 0] * eb[(size_t)(p + 0) * NE];
                s1 += smem[p + 1] * eb[(size_t)(p + 1) * NE];
                s2v += smem[p + 2] * eb[(size_t)(p + 2) * NE];
                s3 += smem[p + 3] * eb[(size_t)(p + 3) * NE];
            }
            float awe = (s0 + s1) + (s2v + s3);
            float gp = b_fb[k];
            #pragma unroll
            for (int ks = 0; ks < 8; ++ks) gp += gatep[((size_t)ks * NB + b) * 2048 + k];
            float gate = 1.f / (1.f + expf(-gp));
            xh[b * 3072 + ND + k] = gate * awe;
            if (kc == 0) {
                bool live = (t < dlens[b]);
                if (tid < NP) out_alpha[((size_t)b * NT + t) * NP + tid] = live ? smem[tid] : 0.f;
                const float* er = emb_W + (size_t)caps[sind[b] * NL + t] * ND;
                xh[b * 3072 + tid] = er[tid];
                xh[b * 3072 + 256 + tid] = er[256 + tid];
            }
        }
        sense ^= 1; gbar(cnt, sns, sense);

        // ===== Phase D: LSTM gates GEMM partials (32 ntiles x 8 ksplit of 384)
        {
            int nt = blk & 31, ks = blk >> 5;
            float* As = smem;
            float (*Ws)[33] = (float(*)[33])(smem + 1024);
            int n0 = nt * 64;
            int lb = tid / 8, lkq = tid % 8;
            int b4 = (tid / 32) * 4, nl = (tid % 32) * 2;
            float acc[4][2] = {};
            for (int kt = ks * 384; kt < ks * 384 + 384; kt += 32) {
                float4 a4 = *reinterpret_cast<const float4*>(xh + (size_t)lb * 3072 + kt + lkq * 4);
                As[(lkq * 4 + 0) * 32 + lb] = a4.x; As[(lkq * 4 + 1) * 32 + lb] = a4.y;
                As[(lkq * 4 + 2) * 32 + lb] = a4.z; As[(lkq * 4 + 3) * 32 + lb] = a4.w;
                #pragma unroll
                for (int r = 0; r < 2; ++r) {
                    int s = tid + r * 256;
                    int n_l = s / 8, kq = s % 8;
                    int ng = n0 + n_l;
                    int kk = kt + kq * 4;
                    const float* wrow = (kk < 2560) ? (W_ih + (size_t)ng * 2560 + kk)
                                                    : (W_hh + (size_t)ng * 512 + (kk - 2560));
                    float4 w4 = *reinterpret_cast<const float4*>(wrow);
                    Ws[n_l][kq * 4 + 0] = w4.x; Ws[n_l][kq * 4 + 1] = w4.y;
                    Ws[n_l][kq * 4 + 2] = w4.z; Ws[n_l][kq * 4 + 3] = w4.w;
                }
                __syncthreads();
                #pragma unroll
                for (int k = 0; k < 32; ++k) {
                    float4 av = *reinterpret_cast<const float4*>(&As[k * 32 + b4]);
                    float w0 = Ws[nl][k], w1 = Ws[nl + 1][k];
                    acc[0][0] += av.x * w0; acc[0][1] += av.x * w1;
                    acc[1][0] += av.y * w0; acc[1][1] += av.y * w1;
                    acc[2][0] += av.z * w0; acc[2][1] += av.z * w1;
                    acc[3][0] += av.w * w0; acc[3][1] += av.w * w1;
                }
                __syncthreads();
            }
            float* Cp = gpart + (size_t)ks * NB * 2048;
            #pragma unroll
            for (int j = 0; j < 2; ++j)
                #pragma unroll
                for (int i = 0; i < 4; ++i)
                    Cp[(size_t)(b4 + i) * 2048 + n0 + nl + j] = acc[i][j];
        }
        sense ^= 1; gbar(cnt, sns, sense);

        // ===== Phase E: reduce partials + LSTM cell (blocks 0..63)
        if (blk < 64) {
            int b = blk >> 1, d = (blk & 1) * 256 + tid;
            float g[4];
            #pragma unroll
            for (int q = 0; q < 4; ++q) {
                float s = b_ih[q * 512 + d] + b_hh[q * 512 + d];
                #pragma unroll
                for (int ks = 0; ks < 8; ++ks)
                    s += gpart[((size_t)ks * NB + b) * 2048 + q * 512 + d];
                g[q] = s;
            }
            float ig = 1.f / (1.f + expf(-g[0]));
            float fg = 1.f / (1.f + expf(-g[1]));
            float gg = tanhf(g[2]);
            float og = 1.f / (1.f + expf(-g[3]));
            float c_old = hc[b * 1024 + 512 + d];
            float c_new = fg * c_old + ig * gg;
            float h_new = og * tanhf(c_new);
            hseq[((size_t)t * NB + b) * ND + d] = h_new;
            if (t < dlens[b]) {
                hc[b * 1024 + d] = h_new;
                hc[b * 1024 + 512 + d] = c_new;
                xh[b * 3072 + 2560 + d] = h_new;
            }
        }
        sense ^= 1; gbar(cnt, sns, sense);
    }
}

// ---------------- launcher ----------------
extern "C" void kernel_launch(void* const* d_in, const int* in_sizes, int n_in,
                              void* d_out, int out_size, void* d_ws, size_t ws_size,
                              hipStream_t stream)
{
    const float* enc   = (const float*)d_in[0];
    const int*   caps  = (const int*)d_in[1];
    const int*   clens = (const int*)d_in[2];
    const float* emb_W = (const float*)d_in[3];
    const float* W_ea  = (const float*)d_in[4];
    const float* b_ea  = (const float*)d_in[5];
    const float* W_da  = (const float*)d_in[6];
    const float* b_da  = (const float*)d_in[7];
    const float* w_fa  = (const float*)d_in[8];
    const float* b_fa  = (const float*)d_in[9];
    const float* W_ih  = (const float*)d_in[10];
    const float* b_ih  = (const float*)d_in[11];
    const float* W_hh  = (const float*)d_in[12];
    const float* b_hh  = (const float*)d_in[13];
    const float* W_h0  = (const float*)d_in[14];
    const float* b_h0  = (const float*)d_in[15];
    const float* W_c0  = (const float*)d_in[16];
    const float* b_c0  = (const float*)d_in[17];
    const float* W_fb  = (const float*)d_in[18];
    const float* b_fb  = (const float*)d_in[19];
    const float* W_fc  = (const float*)d_in[20];
    const float* b_fc  = (const float*)d_in[21];

    float* out = (float*)d_out;
    float* out_alpha = out + (size_t)NB * NT * NV;

    int* iws    = (int*)d_ws;
    int* sind   = iws;
    int* dlens  = iws + 32;
    int* rowmap = iws + 64;
    int* mpad   = iws + 704;
    unsigned* barst = (unsigned*)(iws + 706);
    float* base = (float*)d_ws + 1024;
    float* mean_enc = base;                       // 65536
    float* hc    = mean_enc + NB * NE;            // 32768
    float* e     = hc + NB * 1024;                // 6272
    float* xh    = e + NB * NP;                   // 98304
    float* gatep = xh + NB * 3072;                // 8*32*2048 = 524288
    float* gpart = gatep + 8 * NB * 2048;         // 8*32*2048 = 524288
    float* hseq  = gpart + 8 * NB * 2048;         // 327680
    float* att1  = hseq + (size_t)NT * NB * ND;   // 3211264

    k_sort<<<1, 64, 0, stream>>>(clens, sind, dlens, rowmap, mpad, barst);
    k_zero<<<NB * NT, 256, 0, stream>>>(dlens, out);
    k_mean<<<dim3(NE / 256, NB), 256, 0, stream>>>(enc, sind, mean_enc);
    gemm_skinny<<<dim3(16), 256, 0, stream>>>(mean_enc, W_h0, W_c0, b_h0, b_c0, hc, xh);
    gemm_att1<<<dim3(ND / 64, (NB * NP) / 128), 256, 0, stream>>>(enc, W_ea, b_ea, att1, sind);

    k_loop<<<dim3(256), dim3(256), 0, stream>>>(
        enc, sind, dlens, caps, emb_W, att1, w_fa, b_fa, W_da, b_da,
        W_fb, b_fb, W_ih, b_ih, W_hh, b_hh,
        hc, e, xh, gatep, gpart, hseq, out_alpha, barst);

    gemm_preds<<<dim3(10, NV / 128), 256, 0, stream>>>(hseq, W_fc, b_fc, out, rowmap, mpad);
}

// Round 6
// 4729.745 us; speedup vs baseline: 2.5966x; 2.5966x over previous
//
#include <hip/hip_runtime.h>
#include <cstddef>

#define NB 32      // batch
#define NP 196     // pixels
#define NE 2048    // encoder dim
#define ND 512     // decoder/att/emb dim
#define NV 32000   // vocab
#define NL 21
#define NT 20      // decode steps

// ---------------- setup ----------------

__global__ void k_sort(const int* __restrict__ lens, int* __restrict__ sind, int* __restrict__ dlens,
                       int* __restrict__ rowmap, int* __restrict__ mpad)
{
    int i = threadIdx.x;
    if (i < NB) {
        int li = lens[i];
        int r = 0;
        for (int j = 0; j < NB; ++j) {
            int lj = lens[j];
            if (lj > li || (lj == li && j < i)) ++r;
        }
        sind[r] = i;
        dlens[r] = li - 1;
    }
    __syncthreads();
    if (i == 0) {
        int cnt = 0;
        for (int t = 0; t < NT; ++t)
            for (int b = 0; b < NB; ++b)
                if (t < dlens[b]) rowmap[cnt++] = t * NB + b;
        int pad = (cnt + 63) & ~63;
        for (int r = cnt; r < pad; ++r) rowmap[r] = -1;
        mpad[0] = pad;
    }
}

__global__ __launch_bounds__(256) void k_mean(const float* __restrict__ enc, const int* __restrict__ sind,
                                              float* __restrict__ mean_enc)
{
    int b = blockIdx.y;
    int k = blockIdx.x * 256 + threadIdx.x;
    const float* e = enc + (size_t)sind[b] * NP * NE + k;
    float s0 = 0.f, s1 = 0.f, s2 = 0.f, s3 = 0.f;
    for (int p = 0; p < NP; p += 4) {
        s0 += e[(size_t)(p + 0) * NE];
        s1 += e[(size_t)(p + 1) * NE];
        s2 += e[(size_t)(p + 2) * NE];
        s3 += e[(size_t)(p + 3) * NE];
    }
    mean_enc[(size_t)b * NE + k] = (s0 + s1 + s2 + s3) * (1.0f / NP);
}

__global__ __launch_bounds__(256) void k_zero(const int* __restrict__ dlens, float* __restrict__ out)
{
    int b = blockIdx.x / NT, t = blockIdx.x % NT;
    if (t < dlens[b]) return;
    float4 z = {0.f, 0.f, 0.f, 0.f};
    float4* row = (float4*)(out + ((size_t)b * NT + t) * NV);
    for (int i = threadIdx.x; i < NV / 4; i += 256) row[i] = z;
}

// ---------------- skinny GEMM (h0/c0; also seeds xh h-part) ----------------
__global__ __launch_bounds__(256) void gemm_skinny(
    const float* __restrict__ A0, const float* __restrict__ W0a, const float* __restrict__ W0b,
    const float* __restrict__ ba, const float* __restrict__ bb,
    float* __restrict__ C, float* __restrict__ xh)
{
    __shared__ float As[32][32];
    __shared__ float Ws[64][33];
    int n0 = blockIdx.x * 64;
    int tid = threadIdx.x;
    int lb = tid / 8, lkq = tid % 8;
    int b4 = (tid / 32) * 4, nl = (tid % 32) * 2;
    float acc[4][2] = {};
    for (int kt = 0; kt < NE; kt += 32) {
        float4 a4 = *reinterpret_cast<const float4*>(A0 + (size_t)lb * NE + kt + lkq * 4);
        As[lkq * 4 + 0][lb] = a4.x; As[lkq * 4 + 1][lb] = a4.y;
        As[lkq * 4 + 2][lb] = a4.z; As[lkq * 4 + 3][lb] = a4.w;
        #pragma unroll
        for (int r = 0; r < 2; ++r) {
            int s = tid + r * 256;
            int n_l = s / 8, kq = s % 8;
            int ng = n0 + n_l;
            const float* wrow = (ng < 512) ? (W0a + (size_t)ng * NE)
                                           : (W0b + (size_t)(ng - 512) * NE);
            float4 w4 = *reinterpret_cast<const float4*>(wrow + kt + kq * 4);
            Ws[n_l][kq * 4 + 0] = w4.x; Ws[n_l][kq * 4 + 1] = w4.y;
            Ws[n_l][kq * 4 + 2] = w4.z; Ws[n_l][kq * 4 + 3] = w4.w;
        }
        __syncthreads();
        #pragma unroll
        for (int k = 0; k < 32; ++k) {
            float4 av = *reinterpret_cast<const float4*>(&As[k][b4]);
            float w0 = Ws[nl][k], w1 = Ws[nl + 1][k];
            acc[0][0] += av.x * w0; acc[0][1] += av.x * w1;
            acc[1][0] += av.y * w0; acc[1][1] += av.y * w1;
            acc[2][0] += av.z * w0; acc[2][1] += av.z * w1;
            acc[3][0] += av.w * w0; acc[3][1] += av.w * w1;
        }
        __syncthreads();
    }
    #pragma unroll
    for (int j = 0; j < 2; ++j) {
        int ng = n0 + nl + j;
        float bias = (ng < 512) ? ba[ng] : bb[ng - 512];
        #pragma unroll
        for (int i = 0; i < 4; ++i) {
            float v = acc[i][j] + bias;
            int b = b4 + i;
            C[(size_t)b * 1024 + ng] = v;
            if (ng < 512) xh[(size_t)b * 3072 + 2560 + ng] = v;
        }
    }
}

// ---------------- att1 GEMM: BM=128 BN=64, 8x4/thread ----------------
__global__ __launch_bounds__(256) void gemm_att1(
    const float* __restrict__ A, const float* __restrict__ W, const float* __restrict__ bias,
    float* __restrict__ C, const int* __restrict__ sind)
{
    __shared__ float As[16][128];
    __shared__ float Ws[16][64];
    int bn0 = blockIdx.x * 64, bm0 = blockIdx.y * 128;
    int tid = threadIdx.x;
    int ty = tid / 16, tx = tid % 16;
    int lm = tid / 4, lk = (tid % 4) * 4;
    int mg0 = bm0 + lm, mg1 = bm0 + 64 + lm;
    const float* arow0 = A + ((size_t)sind[mg0 / NP] * NP + mg0 % NP) * NE;
    const float* arow1 = A + ((size_t)sind[mg1 / NP] * NP + mg1 % NP) * NE;
    const float* wrow = W + (size_t)(bn0 + lm) * NE;
    float4 bias4 = *reinterpret_cast<const float4*>(bias + bn0 + tx * 4);
    float acc[8][4] = {};
    for (int kt = 0; kt < NE; kt += 16) {
        float4 a0 = *reinterpret_cast<const float4*>(arow0 + kt + lk);
        float4 a1 = *reinterpret_cast<const float4*>(arow1 + kt + lk);
        float4 w4 = *reinterpret_cast<const float4*>(wrow + kt + lk);
        As[lk + 0][lm] = a0.x; As[lk + 1][lm] = a0.y; As[lk + 2][lm] = a0.z; As[lk + 3][lm] = a0.w;
        As[lk + 0][64 + lm] = a1.x; As[lk + 1][64 + lm] = a1.y; As[lk + 2][64 + lm] = a1.z; As[lk + 3][64 + lm] = a1.w;
        Ws[lk + 0][lm] = w4.x; Ws[lk + 1][lm] = w4.y; Ws[lk + 2][lm] = w4.z; Ws[lk + 3][lm] = w4.w;
        __syncthreads();
        #pragma unroll
        for (int k = 0; k < 16; ++k) {
            float4 av0 = *reinterpret_cast<const float4*>(&As[k][ty * 8]);
            float4 av1 = *reinterpret_cast<const float4*>(&As[k][ty * 8 + 4]);
            float4 wv = *reinterpret_cast<const float4*>(&Ws[k][tx * 4]);
            acc[0][0] += av0.x * wv.x; acc[0][1] += av0.x * wv.y; acc[0][2] += av0.x * wv.z; acc[0][3] += av0.x * wv.w;
            acc[1][0] += av0.y * wv.x; acc[1][1] += av0.y * wv.y; acc[1][2] += av0.y * wv.z; acc[1][3] += av0.y * wv.w;
            acc[2][0] += av0.z * wv.x; acc[2][1] += av0.z * wv.y; acc[2][2] += av0.z * wv.z; acc[2][3] += av0.z * wv.w;
            acc[3][0] += av0.w * wv.x; acc[3][1] += av0.w * wv.y; acc[3][2] += av0.w * wv.z; acc[3][3] += av0.w * wv.w;
            acc[4][0] += av1.x * wv.x; acc[4][1] += av1.x * wv.y; acc[4][2] += av1.x * wv.z; acc[4][3] += av1.x * wv.w;
            acc[5][0] += av1.y * wv.x; acc[5][1] += av1.y * wv.y; acc[5][2] += av1.y * wv.z; acc[5][3] += av1.y * wv.w;
            acc[6][0] += av1.z * wv.x; acc[6][1] += av1.z * wv.y; acc[6][2] += av1.z * wv.z; acc[6][3] += av1.z * wv.w;
            acc[7][0] += av1.w * wv.x; acc[7][1] += av1.w * wv.y; acc[7][2] += av1.w * wv.z; acc[7][3] += av1.w * wv.w;
        }
        __syncthreads();
    }
    #pragma unroll
    for (int i = 0; i < 8; ++i) {
        int m = bm0 + ty * 8 + i;
        float4 o;
        o.x = acc[i][0] + bias4.x; o.y = acc[i][1] + bias4.y;
        o.z = acc[i][2] + bias4.z; o.w = acc[i][3] + bias4.w;
        *reinterpret_cast<float4*>(C + (size_t)m * ND + bn0 + tx * 4) = o;
    }
}

// ---------------- preds GEMM: BM=64 BN=128, 8x4/thread, live rows only ----------------
__global__ __launch_bounds__(256) void gemm_preds(
    const float* __restrict__ A, const float* __restrict__ W, const float* __restrict__ bias,
    float* __restrict__ C, const int* __restrict__ rowmap, const int* __restrict__ mpad)
{
    int bm0 = blockIdx.x * 64;
    if (bm0 >= mpad[0]) return;
    int bn0 = blockIdx.y * 128;
    __shared__ float As[16][64];
    __shared__ float Ws[16][128];
    int tid = threadIdx.x;
    int ty = tid / 32, tx = tid % 32;
    int lm = tid / 4, lk = (tid % 4) * 4;
    int rid = rowmap[bm0 + lm];
    const float* arow = A + (size_t)(rid < 0 ? 0 : rid) * ND;
    const float* wrow0 = W + (size_t)(bn0 + lm) * ND;
    const float* wrow1 = W + (size_t)(bn0 + 64 + lm) * ND;
    float4 bias4 = *reinterpret_cast<const float4*>(bias + bn0 + tx * 4);
    float acc[8][4] = {};
    for (int kt = 0; kt < ND; kt += 16) {
        float4 a4 = *reinterpret_cast<const float4*>(arow + kt + lk);
        float4 w0 = *reinterpret_cast<const float4*>(wrow0 + kt + lk);
        float4 w1 = *reinterpret_cast<const float4*>(wrow1 + kt + lk);
        As[lk + 0][lm] = a4.x; As[lk + 1][lm] = a4.y; As[lk + 2][lm] = a4.z; As[lk + 3][lm] = a4.w;
        Ws[lk + 0][lm] = w0.x; Ws[lk + 1][lm] = w0.y; Ws[lk + 2][lm] = w0.z; Ws[lk + 3][lm] = w0.w;
        Ws[lk + 0][64 + lm] = w1.x; Ws[lk + 1][64 + lm] = w1.y; Ws[lk + 2][64 + lm] = w1.z; Ws[lk + 3][64 + lm] = w1.w;
        __syncthreads();
        #pragma unroll
        for (int k = 0; k < 16; ++k) {
            float4 av0 = *reinterpret_cast<const float4*>(&As[k][ty * 8]);
            float4 av1 = *reinterpret_cast<const float4*>(&As[k][ty * 8 + 4]);
            float4 wv = *reinterpret_cast<const float4*>(&Ws[k][tx * 4]);
            acc[0][0] += av0.x * wv.x; acc[0][1] += av0.x * wv.y; acc[0][2] += av0.x * wv.z; acc[0][3] += av0.x * wv.w;
            acc[1][0] += av0.y * wv.x; acc[1][1] += av0.y * wv.y; acc[1][2] += av0.y * wv.z; acc[1][3] += av0.y * wv.w;
            acc[2][0] += av0.z * wv.x; acc[2][1] += av0.z * wv.y; acc[2][2] += av0.z * wv.z; acc[2][3] += av0.z * wv.w;
            acc[3][0] += av0.w * wv.x; acc[3][1] += av0.w * wv.y; acc[3][2] += av0.w * wv.z; acc[3][3] += av0.w * wv.w;
            acc[4][0] += av1.x * wv.x; acc[4][1] += av1.x * wv.y; acc[4][2] += av1.x * wv.z; acc[4][3] += av1.x * wv.w;
            acc[5][0] += av1.y * wv.x; acc[5][1] += av1.y * wv.y; acc[5][2] += av1.y * wv.z; acc[5][3] += av1.y * wv.w;
            acc[6][0] += av1.z * wv.x; acc[6][1] += av1.z * wv.y; acc[6][2] += av1.z * wv.z; acc[6][3] += av1.z * wv.w;
            acc[7][0] += av1.w * wv.x; acc[7][1] += av1.w * wv.y; acc[7][2] += av1.w * wv.z; acc[7][3] += av1.w * wv.w;
        }
        __syncthreads();
    }
    #pragma unroll
    for (int i = 0; i < 8; ++i) {
        int rm = rowmap[bm0 + ty * 8 + i];
        if (rm < 0) continue;
        int t = rm / NB, b = rm % NB;
        float4 o;
        o.x = acc[i][0] + bias4.x; o.y = acc[i][1] + bias4.y;
        o.z = acc[i][2] + bias4.z; o.w = acc[i][3] + bias4.w;
        *reinterpret_cast<float4*>(C + ((size_t)b * NT + t) * NV + bn0 + tx * 4) = o;
    }
}

// ---------------- per-step kernel A: gate pre-GEMM (blocks 0..31) + att2+e (blocks 32..63) ----------------
__global__ __launch_bounds__(256) void k_stepA(
    const float* __restrict__ hc, const float* __restrict__ att1,
    const float* __restrict__ W_fb, const float* __restrict__ W_da, const float* __restrict__ b_da,
    const float* __restrict__ w_fa, const float* __restrict__ b_fa,
    float* __restrict__ gatep, float* __restrict__ e)
{
    __shared__ float smem[3200];
    int blk = blockIdx.x, tid = threadIdx.x;
    if (blk < 32) {
        // gatep[b][n] = h[b] . W_fb[n,:]   (n-tile of 64, full K=512)
        float* As = smem;                                   // [32k][32b]
        float (*Ws)[33] = (float(*)[33])(smem + 1024);      // [64][33]
        int n0 = blk * 64;
        int lb = tid / 8, lkq = tid % 8;
        int b4 = (tid / 32) * 4, nl = (tid % 32) * 2;
        float acc[4][2] = {};
        for (int kt = 0; kt < 512; kt += 32) {
            float4 a4 = *reinterpret_cast<const float4*>(hc + (size_t)lb * 1024 + kt + lkq * 4);
            As[(lkq * 4 + 0) * 32 + lb] = a4.x; As[(lkq * 4 + 1) * 32 + lb] = a4.y;
            As[(lkq * 4 + 2) * 32 + lb] = a4.z; As[(lkq * 4 + 3) * 32 + lb] = a4.w;
            #pragma unroll
            for (int r = 0; r < 2; ++r) {
                int s = tid + r * 256;
                int n_l = s / 8, kq = s % 8;
                float4 w4 = *reinterpret_cast<const float4*>(W_fb + (size_t)(n0 + n_l) * ND + kt + kq * 4);
                Ws[n_l][kq * 4 + 0] = w4.x; Ws[n_l][kq * 4 + 1] = w4.y;
                Ws[n_l][kq * 4 + 2] = w4.z; Ws[n_l][kq * 4 + 3] = w4.w;
            }
            __syncthreads();
            #pragma unroll
            for (int k = 0; k < 32; ++k) {
                float4 av = *reinterpret_cast<const float4*>(&As[k * 32 + b4]);
                float w0 = Ws[nl][k], w1 = Ws[nl + 1][k];
                acc[0][0] += av.x * w0; acc[0][1] += av.x * w1;
                acc[1][0] += av.y * w0; acc[1][1] += av.y * w1;
                acc[2][0] += av.z * w0; acc[2][1] += av.z * w1;
                acc[3][0] += av.w * w0; acc[3][1] += av.w * w1;
            }
            __syncthreads();
        }
        #pragma unroll
        for (int j = 0; j < 2; ++j)
            #pragma unroll
            for (int i = 0; i < 4; ++i)
                gatep[(size_t)(b4 + i) * 2048 + n0 + nl + j] = acc[i][j];
    } else {
        // att2 = W_da h + b_da ; e = relu(att1 + att2) . w_fa + b_fa
        int b = blk - 32;
        smem[512 + tid] = w_fa[tid]; smem[768 + tid] = w_fa[256 + tid];
        smem[1024 + tid] = hc[b * 1024 + tid]; smem[1280 + tid] = hc[b * 1024 + 256 + tid];
        __syncthreads();
        int w = tid >> 6, lane = tid & 63;
        const float* hh = &smem[1024];
        for (int r = 0; r < 128; ++r) {
            int row = w * 128 + r;
            const float* wr = W_da + (size_t)row * ND + lane * 8;
            float4 wa = *reinterpret_cast<const float4*>(wr);
            float4 wb = *reinterpret_cast<const float4*>(wr + 4);
            float4 h0 = *reinterpret_cast<const float4*>(hh + lane * 8);
            float4 h1 = *reinterpret_cast<const float4*>(hh + lane * 8 + 4);
            float s = wa.x * h0.x + wa.y * h0.y + wa.z * h0.z + wa.w * h0.w
                    + wb.x * h1.x + wb.y * h1.y + wb.z * h1.z + wb.w * h1.w;
            for (int off = 32; off > 0; off >>= 1) s += __shfl_down(s, off);
            if (lane == 0) smem[row] = s + b_da[row];
        }
        __syncthreads();
        float bfa = b_fa[0];
        const float* a1 = att1 + (size_t)b * NP * ND;
        for (int i = 0; i < 49; ++i) {
            int p = w + 4 * i;
            const float* row = a1 + (size_t)p * ND;
            float s = 0.f;
            #pragma unroll
            for (int j = 0; j < 2; ++j) {
                int d = j * 256 + lane * 4;
                float4 v = *reinterpret_cast<const float4*>(row + d);
                float4 a2 = *reinterpret_cast<const float4*>(&smem[d]);
                float4 wf = *reinterpret_cast<const float4*>(&smem[512 + d]);
                s += fmaxf(v.x + a2.x, 0.f) * wf.x + fmaxf(v.y + a2.y, 0.f) * wf.y
                   + fmaxf(v.z + a2.z, 0.f) * wf.z + fmaxf(v.w + a2.w, 0.f) * wf.w;
            }
            for (int off = 32; off > 0; off >>= 1) s += __shfl_down(s, off);
            if (lane == 0) e[b * NP + p] = s + bfa;
        }
    }
}

// ---------------- per-step kernel B: softmax + awe + gate + x  (grid 8 x 32) ----------------
__global__ __launch_bounds__(256) void k_stepB(
    const float* __restrict__ enc, const int* __restrict__ sind, const int* __restrict__ dlens,
    const int* __restrict__ caps, const float* __restrict__ emb_W,
    const float* __restrict__ e, const float* __restrict__ gatep, const float* __restrict__ b_fb,
    float* __restrict__ xh, float* __restrict__ out_alpha, int t)
{
    __shared__ float smem[512];
    int kc = blockIdx.x, b = blockIdx.y, tid = threadIdx.x;
    float* red = smem + 256;
    float m = -1e30f;
    if (tid < NP) { float v = e[b * NP + tid]; smem[tid] = v; m = v; }
    red[tid] = m; __syncthreads();
    for (int s2 = 128; s2 > 0; s2 >>= 1) { if (tid < s2) red[tid] = fmaxf(red[tid], red[tid + s2]); __syncthreads(); }
    m = red[0]; __syncthreads();
    float sm = 0.f;
    if (tid < NP) { float v = expf(smem[tid] - m); smem[tid] = v; sm = v; }
    red[tid] = sm; __syncthreads();
    for (int s2 = 128; s2 > 0; s2 >>= 1) { if (tid < s2) red[tid] += red[tid + s2]; __syncthreads(); }
    float inv = 1.0f / red[0]; __syncthreads();
    if (tid < NP) smem[tid] *= inv;
    __syncthreads();

    int k = kc * 256 + tid;
    const float* eb = enc + (size_t)sind[b] * NP * NE + k;
    float s0 = 0.f, s1 = 0.f, s2v = 0.f, s3 = 0.f;
    for (int p = 0; p < 196; p += 4) {
        s0 += smem[p + 0] * eb[(size_t)(p + 0) * NE];
        s1 += smem[p + 1] * eb[(size_t)(p + 1) * NE];
        s2v += smem[p + 2] * eb[(size_t)(p + 2) * NE];
        s3 += smem[p + 3] * eb[(size_t)(p + 3) * NE];
    }
    float awe = (s0 + s1) + (s2v + s3);
    float gp = b_fb[k] + gatep[(size_t)b * 2048 + k];
    float gate = 1.f / (1.f + expf(-gp));
    xh[b * 3072 + ND + k] = gate * awe;
    if (kc == 0) {
        bool live = (t < dlens[b]);
        if (tid < NP) out_alpha[((size_t)b * NT + t) * NP + tid] = live ? smem[tid] : 0.f;
        const float* er = emb_W + (size_t)caps[sind[b] * NL + t] * ND;
        xh[b * 3072 + tid] = er[tid];
        xh[b * 3072 + 256 + tid] = er[256 + tid];
    }
}

// ---------------- per-step kernel C: LSTM gates GEMM + fused cell (grid 64, d-chunks of 8) ----------------
__global__ __launch_bounds__(256) void k_stepC(
    float* xh, const float* __restrict__ W_ih, const float* __restrict__ b_ih,
    const float* __restrict__ W_hh, const float* __restrict__ b_hh,
    const int* __restrict__ dlens, float* __restrict__ hc, float* __restrict__ hseq, int t)
{
    __shared__ float As[32 * 32];     // [k][b]
    __shared__ float Ws[32][33];      // [r][k]
    __shared__ float Gs[32][33];      // exchange [r][b]
    int blk = blockIdx.x, tid = threadIdx.x;
    int d0 = blk * 8;
    int lb = tid / 8, lkq = tid % 8;        // A-load: batch row lb, k-quad lkq
    int r_l = tid / 8, kq = tid % 8;        // W-load: local row r_l, k-quad kq
    int qq = r_l >> 3, ddl = r_l & 7;
    int ng_l = qq * 512 + d0 + ddl;         // global W row for loading
    int b4 = (tid / 32) * 4, rr = tid % 32; // compute: 4 batches x local row rr
    int q = rr >> 3, dd = rr & 7;
    int n = q * 512 + d0 + dd;
    float bias = b_ih[n] + b_hh[n];
    float acc[4] = {bias, bias, bias, bias};
    for (int kt = 0; kt < 3072; kt += 32) {
        float4 a4 = *reinterpret_cast<const float4*>(xh + (size_t)lb * 3072 + kt + lkq * 4);
        As[(lkq * 4 + 0) * 32 + lb] = a4.x; As[(lkq * 4 + 1) * 32 + lb] = a4.y;
        As[(lkq * 4 + 2) * 32 + lb] = a4.z; As[(lkq * 4 + 3) * 32 + lb] = a4.w;
        int kk = kt + kq * 4;
        const float* wrow = (kk < 2560) ? (W_ih + (size_t)ng_l * 2560 + kk)
                                        : (W_hh + (size_t)ng_l * 512 + (kk - 2560));
        float4 w4 = *reinterpret_cast<const float4*>(wrow);
        Ws[r_l][kq * 4 + 0] = w4.x; Ws[r_l][kq * 4 + 1] = w4.y;
        Ws[r_l][kq * 4 + 2] = w4.z; Ws[r_l][kq * 4 + 3] = w4.w;
        __syncthreads();
        #pragma unroll
        for (int k = 0; k < 32; ++k) {
            float4 av = *reinterpret_cast<const float4*>(&As[k * 32 + b4]);
            float wv = Ws[rr][k];
            acc[0] += av.x * wv; acc[1] += av.y * wv;
            acc[2] += av.z * wv; acc[3] += av.w * wv;
        }
        __syncthreads();
    }
    #pragma unroll
    for (int i = 0; i < 4; ++i) Gs[rr][b4 + i] = acc[i];
    __syncthreads();
    if (rr < 8) {
        int d = d0 + rr;
        #pragma unroll
        for (int i = 0; i < 4; ++i) {
            int b = b4 + i;
            float gi = Gs[rr][b], gf = Gs[8 + rr][b], gg = Gs[16 + rr][b], go = Gs[24 + rr][b];
            float ig = 1.f / (1.f + expf(-gi));
            float fg = 1.f / (1.f + expf(-gf));
            float gt = tanhf(gg);
            float og = 1.f / (1.f + expf(-go));
            float c_old = hc[(size_t)b * 1024 + 512 + d];
            float c_new = fg * c_old + ig * gt;
            float h_new = og * tanhf(c_new);
            hseq[((size_t)t * NB + b) * ND + d] = h_new;
            if (t < dlens[b]) {
                hc[(size_t)b * 1024 + d] = h_new;
                hc[(size_t)b * 1024 + 512 + d] = c_new;
                xh[(size_t)b * 3072 + 2560 + d] = h_new;
            }
        }
    }
}

// ---------------- launcher ----------------
extern "C" void kernel_launch(void* const* d_in, const int* in_sizes, int n_in,
                              void* d_out, int out_size, void* d_ws, size_t ws_size,
                              hipStream_t stream)
{
    const float* enc   = (const float*)d_in[0];
    const int*   caps  = (const int*)d_in[1];
    const int*   clens = (const int*)d_in[2];
    const float* emb_W = (const float*)d_in[3];
    const float* W_ea  = (const float*)d_in[4];
    const float* b_ea  = (const float*)d_in[5];
    const float* W_da  = (const float*)d_in[6];
    const float* b_da  = (const float*)d_in[7];
    const float* w_fa  = (const float*)d_in[8];
    const float* b_fa  = (const float*)d_in[9];
    const float* W_ih  = (const float*)d_in[10];
    const float* b_ih  = (const float*)d_in[11];
    const float* W_hh  = (const float*)d_in[12];
    const float* b_hh  = (const float*)d_in[13];
    const float* W_h0  = (const float*)d_in[14];
    const float* b_h0  = (const float*)d_in[15];
    const float* W_c0  = (const float*)d_in[16];
    const float* b_c0  = (const float*)d_in[17];
    const float* W_fb  = (const float*)d_in[18];
    const float* b_fb  = (const float*)d_in[19];
    const float* W_fc  = (const float*)d_in[20];
    const float* b_fc  = (const float*)d_in[21];

    float* out = (float*)d_out;
    float* out_alpha = out + (size_t)NB * NT * NV;

    int* iws    = (int*)d_ws;
    int* sind   = iws;
    int* dlens  = iws + 32;
    int* rowmap = iws + 64;
    int* mpad   = iws + 704;
    float* base = (float*)d_ws + 1024;
    float* mean_enc = base;                       // 65536
    float* hc    = mean_enc + NB * NE;            // 32768
    float* e     = hc + NB * 1024;                // 6272
    float* xh    = e + NB * NP;                   // 98304
    float* gatep = xh + NB * 3072;                // 32*2048 = 65536
    float* hseq  = gatep + NB * 2048;             // 327680
    float* att1  = hseq + (size_t)NT * NB * ND;   // 3211264

    k_sort<<<1, 64, 0, stream>>>(clens, sind, dlens, rowmap, mpad);
    k_zero<<<NB * NT, 256, 0, stream>>>(dlens, out);
    k_mean<<<dim3(NE / 256, NB), 256, 0, stream>>>(enc, sind, mean_enc);
    gemm_skinny<<<dim3(16), 256, 0, stream>>>(mean_enc, W_h0, W_c0, b_h0, b_c0, hc, xh);
    gemm_att1<<<dim3(ND / 64, (NB * NP) / 128), 256, 0, stream>>>(enc, W_ea, b_ea, att1, sind);

    for (int t = 0; t < NT; ++t) {
        k_stepA<<<dim3(64), 256, 0, stream>>>(hc, att1, W_fb, W_da, b_da, w_fa, b_fa, gatep, e);
        k_stepB<<<dim3(8, NB), 256, 0, stream>>>(enc, sind, dlens, caps, emb_W,
                                                 e, gatep, b_fb, xh, out_alpha, t);
        k_stepC<<<dim3(64), 256, 0, stream>>>(xh, W_ih, b_ih, W_hh, b_hh, dlens, hc, hseq, t);
    }

    gemm_preds<<<dim3(10, NV / 128), 256, 0, stream>>>(hseq, W_fc, b_fc, out, rowmap, mpad);
}

// Round 7
// 3371.166 us; speedup vs baseline: 3.6430x; 1.4030x over previous
//
#include <hip/hip_runtime.h>
#include <cstddef>

#define NB 32      // batch
#define NP 196     // pixels
#define NE 2048    // encoder dim
#define ND 512     // decoder/att/emb dim
#define NV 32000   // vocab
#define NL 21
#define NT 20      // decode steps
#define KC 4       // k-chunk blocks per batch in k_step

// ---------------- setup ----------------

__global__ void k_sort(const int* __restrict__ lens, int* __restrict__ sind, int* __restrict__ dlens,
                       int* __restrict__ rowmap, int* __restrict__ mpad)
{
    int i = threadIdx.x;
    if (i < NB) {
        int li = lens[i];
        int r = 0;
        for (int j = 0; j < NB; ++j) {
            int lj = lens[j];
            if (lj > li || (lj == li && j < i)) ++r;
        }
        sind[r] = i;
        dlens[r] = li - 1;
    }
    __syncthreads();
    if (i == 0) {
        int cnt = 0;
        for (int t = 0; t < NT; ++t)
            for (int b = 0; b < NB; ++b)
                if (t < dlens[b]) rowmap[cnt++] = t * NB + b;
        int pad = (cnt + 63) & ~63;
        for (int r = cnt; r < pad; ++r) rowmap[r] = -1;
        mpad[0] = pad;
    }
}

__global__ __launch_bounds__(256) void k_mean(const float* __restrict__ enc, const int* __restrict__ sind,
                                              float* __restrict__ mean_enc)
{
    int b = blockIdx.y;
    int k = blockIdx.x * 256 + threadIdx.x;
    const float* e = enc + (size_t)sind[b] * NP * NE + k;
    float s0 = 0.f, s1 = 0.f, s2 = 0.f, s3 = 0.f;
    for (int p = 0; p < NP; p += 4) {
        s0 += e[(size_t)(p + 0) * NE];
        s1 += e[(size_t)(p + 1) * NE];
        s2 += e[(size_t)(p + 2) * NE];
        s3 += e[(size_t)(p + 3) * NE];
    }
    mean_enc[(size_t)b * NE + k] = (s0 + s1 + s2 + s3) * (1.0f / NP);
}

__global__ __launch_bounds__(256) void k_zero(const int* __restrict__ dlens, float* __restrict__ out)
{
    int b = blockIdx.x / NT, t = blockIdx.x % NT;
    if (t < dlens[b]) return;
    float4 z = {0.f, 0.f, 0.f, 0.f};
    float4* row = (float4*)(out + ((size_t)b * NT + t) * NV);
    for (int i = threadIdx.x; i < NV / 4; i += 256) row[i] = z;
}

// ---------------- skinny GEMM: h0/c0 into state buffer 0 ----------------
__global__ __launch_bounds__(256) void gemm_skinny(
    const float* __restrict__ A0, const float* __restrict__ W0a, const float* __restrict__ W0b,
    const float* __restrict__ ba, const float* __restrict__ bb,
    float* __restrict__ C)
{
    __shared__ float As[32][32];
    __shared__ float Ws[64][33];
    int n0 = blockIdx.x * 64;
    int tid = threadIdx.x;
    int lb = tid / 8, lkq = tid % 8;
    int b4 = (tid / 32) * 4, nl = (tid % 32) * 2;
    float acc[4][2] = {};
    for (int kt = 0; kt < NE; kt += 32) {
        float4 a4 = *reinterpret_cast<const float4*>(A0 + (size_t)lb * NE + kt + lkq * 4);
        As[lkq * 4 + 0][lb] = a4.x; As[lkq * 4 + 1][lb] = a4.y;
        As[lkq * 4 + 2][lb] = a4.z; As[lkq * 4 + 3][lb] = a4.w;
        #pragma unroll
        for (int r = 0; r < 2; ++r) {
            int s = tid + r * 256;
            int n_l = s / 8, kq = s % 8;
            int ng = n0 + n_l;
            const float* wrow = (ng < 512) ? (W0a + (size_t)ng * NE)
                                           : (W0b + (size_t)(ng - 512) * NE);
            float4 w4 = *reinterpret_cast<const float4*>(wrow + kt + kq * 4);
            Ws[n_l][kq * 4 + 0] = w4.x; Ws[n_l][kq * 4 + 1] = w4.y;
            Ws[n_l][kq * 4 + 2] = w4.z; Ws[n_l][kq * 4 + 3] = w4.w;
        }
        __syncthreads();
        #pragma unroll
        for (int k = 0; k < 32; ++k) {
            float4 av = *reinterpret_cast<const float4*>(&As[k][b4]);
            float w0 = Ws[nl][k], w1 = Ws[nl + 1][k];
            acc[0][0] += av.x * w0; acc[0][1] += av.x * w1;
            acc[1][0] += av.y * w0; acc[1][1] += av.y * w1;
            acc[2][0] += av.z * w0; acc[2][1] += av.z * w1;
            acc[3][0] += av.w * w0; acc[3][1] += av.w * w1;
        }
        __syncthreads();
    }
    #pragma unroll
    for (int j = 0; j < 2; ++j) {
        int ng = n0 + nl + j;
        float bias = (ng < 512) ? ba[ng] : bb[ng - 512];
        #pragma unroll
        for (int i = 0; i < 4; ++i)
            C[(size_t)(b4 + i) * 1024 + ng] = acc[i][j] + bias;
    }
}

// ---------------- att1 GEMM: BM=128 BN=64, 8x4/thread ----------------
__global__ __launch_bounds__(256) void gemm_att1(
    const float* __restrict__ A, const float* __restrict__ W, const float* __restrict__ bias,
    float* __restrict__ C, const int* __restrict__ sind)
{
    __shared__ float As[16][128];
    __shared__ float Ws[16][64];
    int bn0 = blockIdx.x * 64, bm0 = blockIdx.y * 128;
    int tid = threadIdx.x;
    int ty = tid / 16, tx = tid % 16;
    int lm = tid / 4, lk = (tid % 4) * 4;
    int mg0 = bm0 + lm, mg1 = bm0 + 64 + lm;
    const float* arow0 = A + ((size_t)sind[mg0 / NP] * NP + mg0 % NP) * NE;
    const float* arow1 = A + ((size_t)sind[mg1 / NP] * NP + mg1 % NP) * NE;
    const float* wrow = W + (size_t)(bn0 + lm) * NE;
    float4 bias4 = *reinterpret_cast<const float4*>(bias + bn0 + tx * 4);
    float acc[8][4] = {};
    for (int kt = 0; kt < NE; kt += 16) {
        float4 a0 = *reinterpret_cast<const float4*>(arow0 + kt + lk);
        float4 a1 = *reinterpret_cast<const float4*>(arow1 + kt + lk);
        float4 w4 = *reinterpret_cast<const float4*>(wrow + kt + lk);
        As[lk + 0][lm] = a0.x; As[lk + 1][lm] = a0.y; As[lk + 2][lm] = a0.z; As[lk + 3][lm] = a0.w;
        As[lk + 0][64 + lm] = a1.x; As[lk + 1][64 + lm] = a1.y; As[lk + 2][64 + lm] = a1.z; As[lk + 3][64 + lm] = a1.w;
        Ws[lk + 0][lm] = w4.x; Ws[lk + 1][lm] = w4.y; Ws[lk + 2][lm] = w4.z; Ws[lk + 3][lm] = w4.w;
        __syncthreads();
        #pragma unroll
        for (int k = 0; k < 16; ++k) {
            float4 av0 = *reinterpret_cast<const float4*>(&As[k][ty * 8]);
            float4 av1 = *reinterpret_cast<const float4*>(&As[k][ty * 8 + 4]);
            float4 wv = *reinterpret_cast<const float4*>(&Ws[k][tx * 4]);
            acc[0][0] += av0.x * wv.x; acc[0][1] += av0.x * wv.y; acc[0][2] += av0.x * wv.z; acc[0][3] += av0.x * wv.w;
            acc[1][0] += av0.y * wv.x; acc[1][1] += av0.y * wv.y; acc[1][2] += av0.y * wv.z; acc[1][3] += av0.y * wv.w;
            acc[2][0] += av0.z * wv.x; acc[2][1] += av0.z * wv.y; acc[2][2] += av0.z * wv.z; acc[2][3] += av0.z * wv.w;
            acc[3][0] += av0.w * wv.x; acc[3][1] += av0.w * wv.y; acc[3][2] += av0.w * wv.z; acc[3][3] += av0.w * wv.w;
            acc[4][0] += av1.x * wv.x; acc[4][1] += av1.x * wv.y; acc[4][2] += av1.x * wv.z; acc[4][3] += av1.x * wv.w;
            acc[5][0] += av1.y * wv.x; acc[5][1] += av1.y * wv.y; acc[5][2] += av1.y * wv.z; acc[5][3] += av1.y * wv.w;
            acc[6][0] += av1.z * wv.x; acc[6][1] += av1.z * wv.y; acc[6][2] += av1.z * wv.z; acc[6][3] += av1.z * wv.w;
            acc[7][0] += av1.w * wv.x; acc[7][1] += av1.w * wv.y; acc[7][2] += av1.w * wv.z; acc[7][3] += av1.w * wv.w;
        }
        __syncthreads();
    }
    #pragma unroll
    for (int i = 0; i < 8; ++i) {
        int m = bm0 + ty * 8 + i;
        float4 o;
        o.x = acc[i][0] + bias4.x; o.y = acc[i][1] + bias4.y;
        o.z = acc[i][2] + bias4.z; o.w = acc[i][3] + bias4.w;
        *reinterpret_cast<float4*>(C + (size_t)m * ND + bn0 + tx * 4) = o;
    }
}

// ---------------- preds GEMM: BM=64 BN=128, live rows only ----------------
__global__ __launch_bounds__(256) void gemm_preds(
    const float* __restrict__ A, const float* __restrict__ W, const float* __restrict__ bias,
    float* __restrict__ C, const int* __restrict__ rowmap, const int* __restrict__ mpad)
{
    int bm0 = blockIdx.x * 64;
    if (bm0 >= mpad[0]) return;
    int bn0 = blockIdx.y * 128;
    __shared__ float As[16][64];
    __shared__ float Ws[16][128];
    int tid = threadIdx.x;
    int ty = tid / 32, tx = tid % 32;
    int lm = tid / 4, lk = (tid % 4) * 4;
    int rid = rowmap[bm0 + lm];
    const float* arow = A + (size_t)(rid < 0 ? 0 : rid) * ND;
    const float* wrow0 = W + (size_t)(bn0 + lm) * ND;
    const float* wrow1 = W + (size_t)(bn0 + 64 + lm) * ND;
    float4 bias4 = *reinterpret_cast<const float4*>(bias + bn0 + tx * 4);
    float acc[8][4] = {};
    for (int kt = 0; kt < ND; kt += 16) {
        float4 a4 = *reinterpret_cast<const float4*>(arow + kt + lk);
        float4 w0 = *reinterpret_cast<const float4*>(wrow0 + kt + lk);
        float4 w1 = *reinterpret_cast<const float4*>(wrow1 + kt + lk);
        As[lk + 0][lm] = a4.x; As[lk + 1][lm] = a4.y; As[lk + 2][lm] = a4.z; As[lk + 3][lm] = a4.w;
        Ws[lk + 0][lm] = w0.x; Ws[lk + 1][lm] = w0.y; Ws[lk + 2][lm] = w0.z; Ws[lk + 3][lm] = w0.w;
        Ws[lk + 0][64 + lm] = w1.x; Ws[lk + 1][64 + lm] = w1.y; Ws[lk + 2][64 + lm] = w1.z; Ws[lk + 3][64 + lm] = w1.w;
        __syncthreads();
        #pragma unroll
        for (int k = 0; k < 16; ++k) {
            float4 av0 = *reinterpret_cast<const float4*>(&As[k][ty * 8]);
            float4 av1 = *reinterpret_cast<const float4*>(&As[k][ty * 8 + 4]);
            float4 wv = *reinterpret_cast<const float4*>(&Ws[k][tx * 4]);
            acc[0][0] += av0.x * wv.x; acc[0][1] += av0.x * wv.y; acc[0][2] += av0.x * wv.z; acc[0][3] += av0.x * wv.w;
            acc[1][0] += av0.y * wv.x; acc[1][1] += av0.y * wv.y; acc[1][2] += av0.y * wv.z; acc[1][3] += av0.y * wv.w;
            acc[2][0] += av0.z * wv.x; acc[2][1] += av0.z * wv.y; acc[2][2] += av0.z * wv.z; acc[2][3] += av0.z * wv.w;
            acc[3][0] += av0.w * wv.x; acc[3][1] += av0.w * wv.y; acc[3][2] += av0.w * wv.z; acc[3][3] += av0.w * wv.w;
            acc[4][0] += av1.x * wv.x; acc[4][1] += av1.x * wv.y; acc[4][2] += av1.x * wv.z; acc[4][3] += av1.x * wv.w;
            acc[5][0] += av1.y * wv.x; acc[5][1] += av1.y * wv.y; acc[5][2] += av1.y * wv.z; acc[5][3] += av1.y * wv.w;
            acc[6][0] += av1.z * wv.x; acc[6][1] += av1.z * wv.y; acc[6][2] += av1.z * wv.z; acc[6][3] += av1.z * wv.w;
            acc[7][0] += av1.w * wv.x; acc[7][1] += av1.w * wv.y; acc[7][2] += av1.w * wv.z; acc[7][3] += av1.w * wv.w;
        }
        __syncthreads();
    }
    #pragma unroll
    for (int i = 0; i < 8; ++i) {
        int rm = rowmap[bm0 + ty * 8 + i];
        if (rm < 0) continue;
        int t = rm / NB, b = rm % NB;
        float4 o;
        o.x = acc[i][0] + bias4.x; o.y = acc[i][1] + bias4.y;
        o.z = acc[i][2] + bias4.z; o.w = acc[i][3] + bias4.w;
        *reinterpret_cast<float4*>(C + ((size_t)b * NT + t) * NV + bn0 + tx * 4) = o;
    }
}

// ---------------- per-step fused kernel: cell(t-1) + att2 + e + softmax + awe + gate + xh ----------------
// grid (KC=4, NB=32); each block redundantly does cell/att2/e/softmax for its b,
// then its own 512-wide k-chunk of awe+gate. kc==0 block does designated writes.
__global__ __launch_bounds__(256) void k_step(
    const float* __restrict__ enc, const int* __restrict__ sind, const int* __restrict__ dlens,
    const int* __restrict__ caps, const float* __restrict__ emb_W,
    const float* __restrict__ att1,
    const float* __restrict__ w_fa, const float* __restrict__ b_fa,
    const float* __restrict__ W_da, const float* __restrict__ b_da,
    const float* __restrict__ W_fb, const float* __restrict__ b_fb,
    const float* __restrict__ b_ih, const float* __restrict__ b_hh,
    float* __restrict__ hcbuf, const float* __restrict__ gpart,
    float* __restrict__ xh, float* __restrict__ hseq,
    float* __restrict__ out_alpha, int t)
{
    __shared__ float heff[512];
    __shared__ float att2s[512];
    __shared__ float wfas[512];
    __shared__ float al[256];
    __shared__ float red[256];
    int kc = blockIdx.x, b = blockIdx.y, tid = threadIdx.x;

    // ---- phase 1: effective h (finalize cell of step t-1; double-buffered state)
    const float* hcr = hcbuf + (size_t)(((t > 0) ? (t - 1) : 0) & 1) * NB * 1024 + (size_t)b * 1024;
    if (t == 0) {
        for (int d = tid; d < 512; d += 256) heff[d] = hcr[d];
    } else {
        bool live = (t - 1) < dlens[b];
        float* hcw = hcbuf + (size_t)(t & 1) * NB * 1024 + (size_t)b * 1024;
        for (int d = tid; d < 512; d += 256) {
            float g0 = b_ih[d] + b_hh[d];
            float g1 = b_ih[512 + d] + b_hh[512 + d];
            float g2 = b_ih[1024 + d] + b_hh[1024 + d];
            float g3 = b_ih[1536 + d] + b_hh[1536 + d];
            #pragma unroll
            for (int ks = 0; ks < 4; ++ks) {
                const float* gp = gpart + ((size_t)ks * NB + b) * 2048;
                g0 += gp[d]; g1 += gp[512 + d]; g2 += gp[1024 + d]; g3 += gp[1536 + d];
            }
            float ig = 1.f / (1.f + expf(-g0));
            float fg = 1.f / (1.f + expf(-g1));
            float gt = tanhf(g2);
            float og = 1.f / (1.f + expf(-g3));
            float c_old = hcr[512 + d];
            float c_new = fg * c_old + ig * gt;
            float h_new = og * tanhf(c_new);
            float hv = live ? h_new : hcr[d];
            float cv = live ? c_new : c_old;
            heff[d] = hv;
            if (kc == 0) {
                hseq[((size_t)(t - 1) * NB + b) * 512 + d] = h_new;
                hcw[d] = hv; hcw[512 + d] = cv;
            }
        }
    }
    for (int d = tid; d < 512; d += 256) wfas[d] = w_fa[d];
    __syncthreads();

    // ---- phase 2: att2 = W_da . heff + b_da (thread-per-2-rows, reg accumulate)
    for (int r = tid; r < 512; r += 256) {
        const float* wr = W_da + (size_t)r * 512;
        float s0 = 0.f, s1 = 0.f;
        #pragma unroll 8
        for (int k = 0; k < 512; k += 8) {
            float4 wa = *reinterpret_cast<const float4*>(wr + k);
            float4 wb = *reinterpret_cast<const float4*>(wr + k + 4);
            float4 ha = *reinterpret_cast<const float4*>(&heff[k]);
            float4 hb = *reinterpret_cast<const float4*>(&heff[k + 4]);
            s0 += wa.x * ha.x + wa.y * ha.y + wa.z * ha.z + wa.w * ha.w;
            s1 += wb.x * hb.x + wb.y * hb.y + wb.z * hb.z + wb.w * hb.w;
        }
        att2s[r] = s0 + s1 + b_da[r];
    }
    __syncthreads();

    // ---- phase 3: e scores (thread-per-p) + softmax
    float ev = -1e30f;
    if (tid < NP) {
        const float* ar = att1 + ((size_t)b * NP + tid) * 512;
        float s0 = 0.f, s1 = 0.f;
        #pragma unroll 8
        for (int k = 0; k < 512; k += 8) {
            float4 v  = *reinterpret_cast<const float4*>(ar + k);
            float4 v2 = *reinterpret_cast<const float4*>(ar + k + 4);
            float4 a2 = *reinterpret_cast<const float4*>(&att2s[k]);
            float4 a3 = *reinterpret_cast<const float4*>(&att2s[k + 4]);
            float4 wf = *reinterpret_cast<const float4*>(&wfas[k]);
            float4 wf2 = *reinterpret_cast<const float4*>(&wfas[k + 4]);
            s0 += fmaxf(v.x + a2.x, 0.f) * wf.x + fmaxf(v.y + a2.y, 0.f) * wf.y
                + fmaxf(v.z + a2.z, 0.f) * wf.z + fmaxf(v.w + a2.w, 0.f) * wf.w;
            s1 += fmaxf(v2.x + a3.x, 0.f) * wf2.x + fmaxf(v2.y + a3.y, 0.f) * wf2.y
                + fmaxf(v2.z + a3.z, 0.f) * wf2.z + fmaxf(v2.w + a3.w, 0.f) * wf2.w;
        }
        ev = s0 + s1 + b_fa[0];
    }
    red[tid] = ev; __syncthreads();
    for (int s = 128; s > 0; s >>= 1) { if (tid < s) red[tid] = fmaxf(red[tid], red[tid + s]); __syncthreads(); }
    float m = red[0]; __syncthreads();
    float xe = (tid < NP) ? expf(ev - m) : 0.f;
    red[tid] = xe; __syncthreads();
    for (int s = 128; s > 0; s >>= 1) { if (tid < s) red[tid] += red[tid + s]; __syncthreads(); }
    float inv = 1.0f / red[0];
    __syncthreads();
    al[tid] = xe * inv;          // alpha (only [0,196) meaningful)
    __syncthreads();

    // ---- phase 4: awe + gate for this block's 512 k-columns
    const float* encb = enc + (size_t)sind[b] * NP * NE;
    #pragma unroll
    for (int j = 0; j < 2; ++j) {
        int k = kc * 512 + j * 256 + tid;
        const float* ec = encb + k;
        float s0 = 0.f, s1 = 0.f, s2 = 0.f, s3 = 0.f;
        #pragma unroll 4
        for (int p = 0; p < NP; p += 4) {
            s0 += al[p + 0] * ec[(size_t)(p + 0) * NE];
            s1 += al[p + 1] * ec[(size_t)(p + 1) * NE];
            s2 += al[p + 2] * ec[(size_t)(p + 2) * NE];
            s3 += al[p + 3] * ec[(size_t)(p + 3) * NE];
        }
        float awe = (s0 + s1) + (s2 + s3);
        const float* wg = W_fb + (size_t)k * 512;
        float g0 = 0.f, g1 = 0.f;
        #pragma unroll 8
        for (int kk = 0; kk < 512; kk += 8) {
            float4 wa = *reinterpret_cast<const float4*>(wg + kk);
            float4 wb = *reinterpret_cast<const float4*>(wg + kk + 4);
            float4 ha = *reinterpret_cast<const float4*>(&heff[kk]);
            float4 hb = *reinterpret_cast<const float4*>(&heff[kk + 4]);
            g0 += wa.x * ha.x + wa.y * ha.y + wa.z * ha.z + wa.w * ha.w;
            g1 += wb.x * hb.x + wb.y * hb.y + wb.z * hb.z + wb.w * hb.w;
        }
        float gp = g0 + g1 + b_fb[k];
        float gate = 1.f / (1.f + expf(-gp));
        xh[(size_t)b * 3072 + 512 + k] = gate * awe;
    }

    // ---- phase 5: designated writes
    if (kc == 0) {
        bool livet = t < dlens[b];
        if (tid < NP) out_alpha[((size_t)b * NT + t) * NP + tid] = livet ? al[tid] : 0.f;
        const float* er = emb_W + (size_t)caps[sind[b] * NL + t] * 512;
        for (int d = tid; d < 512; d += 256) {
            xh[(size_t)b * 3072 + d] = er[d];
            xh[(size_t)b * 3072 + 2560 + d] = heff[d];
        }
    }
}

// ---------------- gates GEMM: 32 n-tiles x 4 k-splits (R5-proven body) ----------------
__global__ __launch_bounds__(256) void k_gates(
    const float* __restrict__ xh, const float* __restrict__ W_ih, const float* __restrict__ W_hh,
    float* __restrict__ gpart)
{
    __shared__ float smem[3200];
    int blk = blockIdx.x, tid = threadIdx.x;
    int nt = blk & 31, ks = blk >> 5;
    float* As = smem;
    float (*Ws)[33] = (float(*)[33])(smem + 1024);
    int n0 = nt * 64;
    int lb = tid / 8, lkq = tid % 8;
    int b4 = (tid / 32) * 4, nl = (tid % 32) * 2;
    float acc[4][2] = {};
    for (int kt = ks * 768; kt < ks * 768 + 768; kt += 32) {
        float4 a4 = *reinterpret_cast<const float4*>(xh + (size_t)lb * 3072 + kt + lkq * 4);
        As[(lkq * 4 + 0) * 32 + lb] = a4.x; As[(lkq * 4 + 1) * 32 + lb] = a4.y;
        As[(lkq * 4 + 2) * 32 + lb] = a4.z; As[(lkq * 4 + 3) * 32 + lb] = a4.w;
        #pragma unroll
        for (int r = 0; r < 2; ++r) {
            int s = tid + r * 256;
            int n_l = s / 8, kq = s % 8;
            int ng = n0 + n_l;
            int kk = kt + kq * 4;
            const float* wrow = (kk < 2560) ? (W_ih + (size_t)ng * 2560 + kk)
                                            : (W_hh + (size_t)ng * 512 + (kk - 2560));
            float4 w4 = *reinterpret_cast<const float4*>(wrow);
            Ws[n_l][kq * 4 + 0] = w4.x; Ws[n_l][kq * 4 + 1] = w4.y;
            Ws[n_l][kq * 4 + 2] = w4.z; Ws[n_l][kq * 4 + 3] = w4.w;
        }
        __syncthreads();
        #pragma unroll
        for (int k = 0; k < 32; ++k) {
            float4 av = *reinterpret_cast<const float4*>(&As[k * 32 + b4]);
            float w0 = Ws[nl][k], w1 = Ws[nl + 1][k];
            acc[0][0] += av.x * w0; acc[0][1] += av.x * w1;
            acc[1][0] += av.y * w0; acc[1][1] += av.y * w1;
            acc[2][0] += av.z * w0; acc[2][1] += av.z * w1;
            acc[3][0] += av.w * w0; acc[3][1] += av.w * w1;
        }
        __syncthreads();
    }
    float* Cp = gpart + (size_t)ks * NB * 2048;
    #pragma unroll
    for (int j = 0; j < 2; ++j)
        #pragma unroll
        for (int i = 0; i < 4; ++i)
            Cp[(size_t)(b4 + i) * 2048 + n0 + nl + j] = acc[i][j];
}

// ---------------- final cell: hseq[NT-1] ----------------
__global__ __launch_bounds__(256) void k_fin(
    const float* __restrict__ gpart, const float* __restrict__ hcbuf,
    const float* __restrict__ b_ih, const float* __restrict__ b_hh,
    float* __restrict__ hseq)
{
    int b = blockIdx.x;
    const float* hcr = hcbuf + (size_t)((NT - 1) & 1) * NB * 1024 + (size_t)b * 1024;
    for (int d = threadIdx.x; d < 512; d += 256) {
        float g0 = b_ih[d] + b_hh[d];
        float g1 = b_ih[512 + d] + b_hh[512 + d];
        float g2 = b_ih[1024 + d] + b_hh[1024 + d];
        float g3 = b_ih[1536 + d] + b_hh[1536 + d];
        #pragma unroll
        for (int ks = 0; ks < 4; ++ks) {
            const float* gp = gpart + ((size_t)ks * NB + b) * 2048;
            g0 += gp[d]; g1 += gp[512 + d]; g2 += gp[1024 + d]; g3 += gp[1536 + d];
        }
        float ig = 1.f / (1.f + expf(-g0));
        float fg = 1.f / (1.f + expf(-g1));
        float gt = tanhf(g2);
        float og = 1.f / (1.f + expf(-g3));
        float c_old = hcr[512 + d];
        float c_new = fg * c_old + ig * gt;
        float h_new = og * tanhf(c_new);
        hseq[((size_t)(NT - 1) * NB + b) * 512 + d] = h_new;
    }
}

// ---------------- launcher ----------------
extern "C" void kernel_launch(void* const* d_in, const int* in_sizes, int n_in,
                              void* d_out, int out_size, void* d_ws, size_t ws_size,
                              hipStream_t stream)
{
    const float* enc   = (const float*)d_in[0];
    const int*   caps  = (const int*)d_in[1];
    const int*   clens = (const int*)d_in[2];
    const float* emb_W = (const float*)d_in[3];
    const float* W_ea  = (const float*)d_in[4];
    const float* b_ea  = (const float*)d_in[5];
    const float* W_da  = (const float*)d_in[6];
    const float* b_da  = (const float*)d_in[7];
    const float* w_fa  = (const float*)d_in[8];
    const float* b_fa  = (const float*)d_in[9];
    const float* W_ih  = (const float*)d_in[10];
    const float* b_ih  = (const float*)d_in[11];
    const float* W_hh  = (const float*)d_in[12];
    const float* b_hh  = (const float*)d_in[13];
    const float* W_h0  = (const float*)d_in[14];
    const float* b_h0  = (const float*)d_in[15];
    const float* W_c0  = (const float*)d_in[16];
    const float* b_c0  = (const float*)d_in[17];
    const float* W_fb  = (const float*)d_in[18];
    const float* b_fb  = (const float*)d_in[19];
    const float* W_fc  = (const float*)d_in[20];
    const float* b_fc  = (const float*)d_in[21];

    float* out = (float*)d_out;
    float* out_alpha = out + (size_t)NB * NT * NV;

    int* iws    = (int*)d_ws;
    int* sind   = iws;
    int* dlens  = iws + 32;
    int* rowmap = iws + 64;
    int* mpad   = iws + 704;
    float* base = (float*)d_ws + 1024;
    float* mean_enc = base;                         // 65536
    float* hcbuf = mean_enc + NB * NE;              // 2*32*1024 = 65536
    float* xh    = hcbuf + 2 * NB * 1024;           // 98304
    float* gpart = xh + NB * 3072;                  // 4*32*2048 = 262144
    float* hseq  = gpart + 4 * NB * 2048;           // 327680
    float* att1  = hseq + (size_t)NT * NB * ND;     // 3211264

    k_sort<<<1, 64, 0, stream>>>(clens, sind, dlens, rowmap, mpad);
    k_zero<<<NB * NT, 256, 0, stream>>>(dlens, out);
    k_mean<<<dim3(NE / 256, NB), 256, 0, stream>>>(enc, sind, mean_enc);
    gemm_skinny<<<dim3(16), 256, 0, stream>>>(mean_enc, W_h0, W_c0, b_h0, b_c0, hcbuf);
    gemm_att1<<<dim3(ND / 64, (NB * NP) / 128), 256, 0, stream>>>(enc, W_ea, b_ea, att1, sind);

    for (int t = 0; t < NT; ++t) {
        k_step<<<dim3(KC, NB), 256, 0, stream>>>(enc, sind, dlens, caps, emb_W, att1,
                                                 w_fa, b_fa, W_da, b_da, W_fb, b_fb,
                                                 b_ih, b_hh, hcbuf, gpart, xh, hseq,
                                                 out_alpha, t);
        k_gates<<<dim3(128), 256, 0, stream>>>(xh, W_ih, W_hh, gpart);
    }
    k_fin<<<dim3(NB), 256, 0, stream>>>(gpart, hcbuf, b_ih, b_hh, hseq);

    gemm_preds<<<dim3(10, NV / 128), 256, 0, stream>>>(hseq, W_fc, b_fc, out, rowmap, mpad);
}

// Round 8
// 2817.954 us; speedup vs baseline: 4.3582x; 1.1963x over previous
//
#include <hip/hip_runtime.h>
#include <cstddef>

#define NB 32      // batch
#define NP 196     // pixels
#define NE 2048    // encoder dim
#define ND 512     // decoder/att/emb dim
#define NV 32000   // vocab
#define NL 21
#define NT 20      // decode steps

// ---------------- setup ----------------

__global__ void k_sort(const int* __restrict__ lens, int* __restrict__ sind, int* __restrict__ dlens,
                       int* __restrict__ rowmap, int* __restrict__ mpad, int* __restrict__ cnt)
{
    int i = threadIdx.x;
    if (i < NB) {
        int li = lens[i];
        int r = 0;
        for (int j = 0; j < NB; ++j) {
            int lj = lens[j];
            if (lj > li || (lj == li && j < i)) ++r;
        }
        sind[r] = i;
        dlens[r] = li - 1;
        cnt[i] = 0;
    }
    __syncthreads();
    if (i == 0) {
        int c = 0;
        for (int t = 0; t < NT; ++t)
            for (int b = 0; b < NB; ++b)
                if (t < dlens[b]) rowmap[c++] = t * NB + b;
        int pad = (c + 63) & ~63;
        for (int r = c; r < pad; ++r) rowmap[r] = -1;
        mpad[0] = pad;
    }
}

__global__ __launch_bounds__(256) void k_mean(const float* __restrict__ enc, const int* __restrict__ sind,
                                              float* __restrict__ mean_enc)
{
    int b = blockIdx.y;
    int k = blockIdx.x * 256 + threadIdx.x;
    const float* e = enc + (size_t)sind[b] * NP * NE + k;
    float s0 = 0.f, s1 = 0.f, s2 = 0.f, s3 = 0.f;
    for (int p = 0; p < NP; p += 4) {
        s0 += e[(size_t)(p + 0) * NE];
        s1 += e[(size_t)(p + 1) * NE];
        s2 += e[(size_t)(p + 2) * NE];
        s3 += e[(size_t)(p + 3) * NE];
    }
    mean_enc[(size_t)b * NE + k] = (s0 + s1 + s2 + s3) * (1.0f / NP);
}

__global__ __launch_bounds__(256) void k_zero(const int* __restrict__ dlens, float* __restrict__ out)
{
    int b = blockIdx.x / NT, t = blockIdx.x % NT;
    if (t < dlens[b]) return;
    float4 z = {0.f, 0.f, 0.f, 0.f};
    float4* row = (float4*)(out + ((size_t)b * NT + t) * NV);
    for (int i = threadIdx.x; i < NV / 4; i += 256) row[i] = z;
}

// ---------------- skinny GEMM: h0/c0 (also seeds xh h-part) ----------------
__global__ __launch_bounds__(256) void gemm_skinny(
    const float* __restrict__ A0, const float* __restrict__ W0a, const float* __restrict__ W0b,
    const float* __restrict__ ba, const float* __restrict__ bb,
    float* __restrict__ C, float* __restrict__ xh)
{
    __shared__ float As[32][32];
    __shared__ float Ws[64][33];
    int n0 = blockIdx.x * 64;
    int tid = threadIdx.x;
    int lb = tid / 8, lkq = tid % 8;
    int b4 = (tid / 32) * 4, nl = (tid % 32) * 2;
    float acc[4][2] = {};
    for (int kt = 0; kt < NE; kt += 32) {
        float4 a4 = *reinterpret_cast<const float4*>(A0 + (size_t)lb * NE + kt + lkq * 4);
        As[lkq * 4 + 0][lb] = a4.x; As[lkq * 4 + 1][lb] = a4.y;
        As[lkq * 4 + 2][lb] = a4.z; As[lkq * 4 + 3][lb] = a4.w;
        #pragma unroll
        for (int r = 0; r < 2; ++r) {
            int s = tid + r * 256;
            int n_l = s / 8, kq = s % 8;
            int ng = n0 + n_l;
            const float* wrow = (ng < 512) ? (W0a + (size_t)ng * NE)
                                           : (W0b + (size_t)(ng - 512) * NE);
            float4 w4 = *reinterpret_cast<const float4*>(wrow + kt + kq * 4);
            Ws[n_l][kq * 4 + 0] = w4.x; Ws[n_l][kq * 4 + 1] = w4.y;
            Ws[n_l][kq * 4 + 2] = w4.z; Ws[n_l][kq * 4 + 3] = w4.w;
        }
        __syncthreads();
        #pragma unroll
        for (int k = 0; k < 32; ++k) {
            float4 av = *reinterpret_cast<const float4*>(&As[k][b4]);
            float w0 = Ws[nl][k], w1 = Ws[nl + 1][k];
            acc[0][0] += av.x * w0; acc[0][1] += av.x * w1;
            acc[1][0] += av.y * w0; acc[1][1] += av.y * w1;
            acc[2][0] += av.z * w0; acc[2][1] += av.z * w1;
            acc[3][0] += av.w * w0; acc[3][1] += av.w * w1;
        }
        __syncthreads();
    }
    #pragma unroll
    for (int j = 0; j < 2; ++j) {
        int ng = n0 + nl + j;
        float bias = (ng < 512) ? ba[ng] : bb[ng - 512];
        #pragma unroll
        for (int i = 0; i < 4; ++i) {
            float v = acc[i][j] + bias;
            int b = b4 + i;
            C[(size_t)b * 1024 + ng] = v;
            if (ng < 512) xh[(size_t)b * 3072 + 2560 + ng] = v;
        }
    }
}

// ---------------- att1 GEMM: BM=128 BN=64, 8x4/thread ----------------
__global__ __launch_bounds__(256) void gemm_att1(
    const float* __restrict__ A, const float* __restrict__ W, const float* __restrict__ bias,
    float* __restrict__ C, const int* __restrict__ sind)
{
    __shared__ float As[16][128];
    __shared__ float Ws[16][64];
    int bn0 = blockIdx.x * 64, bm0 = blockIdx.y * 128;
    int tid = threadIdx.x;
    int ty = tid / 16, tx = tid % 16;
    int lm = tid / 4, lk = (tid % 4) * 4;
    int mg0 = bm0 + lm, mg1 = bm0 + 64 + lm;
    const float* arow0 = A + ((size_t)sind[mg0 / NP] * NP + mg0 % NP) * NE;
    const float* arow1 = A + ((size_t)sind[mg1 / NP] * NP + mg1 % NP) * NE;
    const float* wrow = W + (size_t)(bn0 + lm) * NE;
    float4 bias4 = *reinterpret_cast<const float4*>(bias + bn0 + tx * 4);
    float acc[8][4] = {};
    for (int kt = 0; kt < NE; kt += 16) {
        float4 a0 = *reinterpret_cast<const float4*>(arow0 + kt + lk);
        float4 a1 = *reinterpret_cast<const float4*>(arow1 + kt + lk);
        float4 w4 = *reinterpret_cast<const float4*>(wrow + kt + lk);
        As[lk + 0][lm] = a0.x; As[lk + 1][lm] = a0.y; As[lk + 2][lm] = a0.z; As[lk + 3][lm] = a0.w;
        As[lk + 0][64 + lm] = a1.x; As[lk + 1][64 + lm] = a1.y; As[lk + 2][64 + lm] = a1.z; As[lk + 3][64 + lm] = a1.w;
        Ws[lk + 0][lm] = w4.x; Ws[lk + 1][lm] = w4.y; Ws[lk + 2][lm] = w4.z; Ws[lk + 3][lm] = w4.w;
        __syncthreads();
        #pragma unroll
        for (int k = 0; k < 16; ++k) {
            float4 av0 = *reinterpret_cast<const float4*>(&As[k][ty * 8]);
            float4 av1 = *reinterpret_cast<const float4*>(&As[k][ty * 8 + 4]);
            float4 wv = *reinterpret_cast<const float4*>(&Ws[k][tx * 4]);
            acc[0][0] += av0.x * wv.x; acc[0][1] += av0.x * wv.y; acc[0][2] += av0.x * wv.z; acc[0][3] += av0.x * wv.w;
            acc[1][0] += av0.y * wv.x; acc[1][1] += av0.y * wv.y; acc[1][2] += av0.y * wv.z; acc[1][3] += av0.y * wv.w;
            acc[2][0] += av0.z * wv.x; acc[2][1] += av0.z * wv.y; acc[2][2] += av0.z * wv.z; acc[2][3] += av0.z * wv.w;
            acc[3][0] += av0.w * wv.x; acc[3][1] += av0.w * wv.y; acc[3][2] += av0.w * wv.z; acc[3][3] += av0.w * wv.w;
            acc[4][0] += av1.x * wv.x; acc[4][1] += av1.x * wv.y; acc[4][2] += av1.x * wv.z; acc[4][3] += av1.x * wv.w;
            acc[5][0] += av1.y * wv.x; acc[5][1] += av1.y * wv.y; acc[5][2] += av1.y * wv.z; acc[5][3] += av1.y * wv.w;
            acc[6][0] += av1.z * wv.x; acc[6][1] += av1.z * wv.y; acc[6][2] += av1.z * wv.z; acc[6][3] += av1.z * wv.w;
            acc[7][0] += av1.w * wv.x; acc[7][1] += av1.w * wv.y; acc[7][2] += av1.w * wv.z; acc[7][3] += av1.w * wv.w;
        }
        __syncthreads();
    }
    #pragma unroll
    for (int i = 0; i < 8; ++i) {
        int m = bm0 + ty * 8 + i;
        float4 o;
        o.x = acc[i][0] + bias4.x; o.y = acc[i][1] + bias4.y;
        o.z = acc[i][2] + bias4.z; o.w = acc[i][3] + bias4.w;
        *reinterpret_cast<float4*>(C + (size_t)m * ND + bn0 + tx * 4) = o;
    }
}

// ---------------- preds GEMM: BM=64 BN=128, live rows only ----------------
__global__ __launch_bounds__(256) void gemm_preds(
    const float* __restrict__ A, const float* __restrict__ W, const float* __restrict__ bias,
    float* __restrict__ C, const int* __restrict__ rowmap, const int* __restrict__ mpad)
{
    int bm0 = blockIdx.x * 64;
    if (bm0 >= mpad[0]) return;
    int bn0 = blockIdx.y * 128;
    __shared__ float As[16][64];
    __shared__ float Ws[16][128];
    int tid = threadIdx.x;
    int ty = tid / 32, tx = tid % 32;
    int lm = tid / 4, lk = (tid % 4) * 4;
    int rid = rowmap[bm0 + lm];
    const float* arow = A + (size_t)(rid < 0 ? 0 : rid) * ND;
    const float* wrow0 = W + (size_t)(bn0 + lm) * ND;
    const float* wrow1 = W + (size_t)(bn0 + 64 + lm) * ND;
    float4 bias4 = *reinterpret_cast<const float4*>(bias + bn0 + tx * 4);
    float acc[8][4] = {};
    for (int kt = 0; kt < ND; kt += 16) {
        float4 a4 = *reinterpret_cast<const float4*>(arow + kt + lk);
        float4 w0 = *reinterpret_cast<const float4*>(wrow0 + kt + lk);
        float4 w1 = *reinterpret_cast<const float4*>(wrow1 + kt + lk);
        As[lk + 0][lm] = a4.x; As[lk + 1][lm] = a4.y; As[lk + 2][lm] = a4.z; As[lk + 3][lm] = a4.w;
        Ws[lk + 0][lm] = w0.x; Ws[lk + 1][lm] = w0.y; Ws[lk + 2][lm] = w0.z; Ws[lk + 3][lm] = w0.w;
        Ws[lk + 0][64 + lm] = w1.x; Ws[lk + 1][64 + lm] = w1.y; Ws[lk + 2][64 + lm] = w1.z; Ws[lk + 3][64 + lm] = w1.w;
        __syncthreads();
        #pragma unroll
        for (int k = 0; k < 16; ++k) {
            float4 av0 = *reinterpret_cast<const float4*>(&As[k][ty * 8]);
            float4 av1 = *reinterpret_cast<const float4*>(&As[k][ty * 8 + 4]);
            float4 wv = *reinterpret_cast<const float4*>(&Ws[k][tx * 4]);
            acc[0][0] += av0.x * wv.x; acc[0][1] += av0.x * wv.y; acc[0][2] += av0.x * wv.z; acc[0][3] += av0.x * wv.w;
            acc[1][0] += av0.y * wv.x; acc[1][1] += av0.y * wv.y; acc[1][2] += av0.y * wv.z; acc[1][3] += av0.y * wv.w;
            acc[2][0] += av0.z * wv.x; acc[2][1] += av0.z * wv.y; acc[2][2] += av0.z * wv.z; acc[2][3] += av0.z * wv.w;
            acc[3][0] += av0.w * wv.x; acc[3][1] += av0.w * wv.y; acc[3][2] += av0.w * wv.z; acc[3][3] += av0.w * wv.w;
            acc[4][0] += av1.x * wv.x; acc[4][1] += av1.x * wv.y; acc[4][2] += av1.x * wv.z; acc[4][3] += av1.x * wv.w;
            acc[5][0] += av1.y * wv.x; acc[5][1] += av1.y * wv.y; acc[5][2] += av1.y * wv.z; acc[5][3] += av1.y * wv.w;
            acc[6][0] += av1.z * wv.x; acc[6][1] += av1.z * wv.y; acc[6][2] += av1.z * wv.z; acc[6][3] += av1.z * wv.w;
            acc[7][0] += av1.w * wv.x; acc[7][1] += av1.w * wv.y; acc[7][2] += av1.w * wv.z; acc[7][3] += av1.w * wv.w;
        }
        __syncthreads();
    }
    #pragma unroll
    for (int i = 0; i < 8; ++i) {
        int rm = rowmap[bm0 + ty * 8 + i];
        if (rm < 0) continue;
        int t = rm / NB, b = rm % NB;
        float4 o;
        o.x = acc[i][0] + bias4.x; o.y = acc[i][1] + bias4.y;
        o.z = acc[i][2] + bias4.z; o.w = acc[i][3] + bias4.w;
        *reinterpret_cast<float4*>(C + ((size_t)b * NT + t) * NV + bn0 + tx * 4) = o;
    }
}

// ---------------- kA: att2|gate pre-GEMM (40 blocks): attg[32][2560] = h @ [W_da;W_fb]^T + [b_da;b_fb]
__global__ __launch_bounds__(256) void k_stepA(
    const float* __restrict__ hc, const float* __restrict__ W_da, const float* __restrict__ W_fb,
    const float* __restrict__ b_da, const float* __restrict__ b_fb,
    float* __restrict__ attg)
{
    __shared__ float As[32][32];
    __shared__ float Ws[64][33];
    int n0 = blockIdx.x * 64;
    int tid = threadIdx.x;
    int lb = tid / 8, lkq = tid % 8;
    int b4 = (tid / 32) * 4, nl = (tid % 32) * 2;
    float acc[4][2] = {};
    for (int kt = 0; kt < 512; kt += 32) {
        float4 a4 = *reinterpret_cast<const float4*>(hc + (size_t)lb * 1024 + kt + lkq * 4);
        As[lkq * 4 + 0][lb] = a4.x; As[lkq * 4 + 1][lb] = a4.y;
        As[lkq * 4 + 2][lb] = a4.z; As[lkq * 4 + 3][lb] = a4.w;
        #pragma unroll
        for (int r = 0; r < 2; ++r) {
            int s = tid + r * 256;
            int n_l = s / 8, kq = s % 8;
            int ng = n0 + n_l;
            const float* wrow = (ng < 512) ? (W_da + (size_t)ng * 512)
                                           : (W_fb + (size_t)(ng - 512) * 512);
            float4 w4 = *reinterpret_cast<const float4*>(wrow + kt + kq * 4);
            Ws[n_l][kq * 4 + 0] = w4.x; Ws[n_l][kq * 4 + 1] = w4.y;
            Ws[n_l][kq * 4 + 2] = w4.z; Ws[n_l][kq * 4 + 3] = w4.w;
        }
        __syncthreads();
        #pragma unroll
        for (int k = 0; k < 32; ++k) {
            float4 av = *reinterpret_cast<const float4*>(&As[k][b4]);
            float w0 = Ws[nl][k], w1 = Ws[nl + 1][k];
            acc[0][0] += av.x * w0; acc[0][1] += av.x * w1;
            acc[1][0] += av.y * w0; acc[1][1] += av.y * w1;
            acc[2][0] += av.z * w0; acc[2][1] += av.z * w1;
            acc[3][0] += av.w * w0; acc[3][1] += av.w * w1;
        }
        __syncthreads();
    }
    #pragma unroll
    for (int j = 0; j < 2; ++j) {
        int ng = n0 + nl + j;
        float bias = (ng < 512) ? b_da[ng] : b_fb[ng - 512];
        #pragma unroll
        for (int i = 0; i < 4; ++i)
            attg[(size_t)(b4 + i) * 2560 + ng] = acc[i][j] + bias;
    }
}

// ---------------- kB: e + softmax + awe + gate + xh (grid 8 x 32) ----------------
__global__ __launch_bounds__(256) void k_stepB(
    const float* __restrict__ enc, const int* __restrict__ sind, const int* __restrict__ dlens,
    const int* __restrict__ caps, const float* __restrict__ emb_W,
    const float* __restrict__ att1, const float* __restrict__ attg,
    const float* __restrict__ w_fa, const float* __restrict__ b_fa,
    float* __restrict__ xh, float* __restrict__ out_alpha, int t)
{
    __shared__ float att2s[512];
    __shared__ float wfas[512];
    __shared__ float es[256];
    __shared__ float red[256];
    int kc = blockIdx.x, b = blockIdx.y, tid = threadIdx.x;
    const float* ag = attg + (size_t)b * 2560;
    att2s[tid] = ag[tid]; att2s[256 + tid] = ag[256 + tid];
    wfas[tid] = w_fa[tid]; wfas[256 + tid] = w_fa[256 + tid];
    __syncthreads();
    // e scores: wave-per-p, coalesced, shuffle reduce
    int w = tid >> 6, lane = tid & 63;
    float bfa = b_fa[0];
    const float* a1 = att1 + (size_t)b * NP * ND;
    for (int i = 0; i < 49; ++i) {
        int p = w + 4 * i;
        const float* row = a1 + (size_t)p * ND;
        float s = 0.f;
        #pragma unroll
        for (int j = 0; j < 2; ++j) {
            int d = j * 256 + lane * 4;
            float4 v = *reinterpret_cast<const float4*>(row + d);
            float4 a2 = *reinterpret_cast<const float4*>(&att2s[d]);
            float4 wf = *reinterpret_cast<const float4*>(&wfas[d]);
            s += fmaxf(v.x + a2.x, 0.f) * wf.x + fmaxf(v.y + a2.y, 0.f) * wf.y
               + fmaxf(v.z + a2.z, 0.f) * wf.z + fmaxf(v.w + a2.w, 0.f) * wf.w;
        }
        for (int off = 32; off > 0; off >>= 1) s += __shfl_down(s, off);
        if (lane == 0) es[p] = s + bfa;
    }
    __syncthreads();
    // softmax over es[0..195]
    float ev = (tid < NP) ? es[tid] : -1e30f;
    red[tid] = ev; __syncthreads();
    for (int s2 = 128; s2 > 0; s2 >>= 1) { if (tid < s2) red[tid] = fmaxf(red[tid], red[tid + s2]); __syncthreads(); }
    float m = red[0]; __syncthreads();
    float xe = (tid < NP) ? expf(ev - m) : 0.f;
    red[tid] = xe; __syncthreads();
    for (int s2 = 128; s2 > 0; s2 >>= 1) { if (tid < s2) red[tid] += red[tid + s2]; __syncthreads(); }
    float inv = 1.0f / red[0];
    __syncthreads();
    es[tid] = xe * inv;
    __syncthreads();
    // awe + gate for this block's 256 k-columns
    int k = kc * 256 + tid;
    const float* ec = enc + (size_t)sind[b] * NP * NE + k;
    float s0 = 0.f, s1 = 0.f, s2v = 0.f, s3 = 0.f;
    #pragma unroll 4
    for (int p = 0; p < NP; p += 4) {
        s0 += es[p + 0] * ec[(size_t)(p + 0) * NE];
        s1 += es[p + 1] * ec[(size_t)(p + 1) * NE];
        s2v += es[p + 2] * ec[(size_t)(p + 2) * NE];
        s3 += es[p + 3] * ec[(size_t)(p + 3) * NE];
    }
    float awe = (s0 + s1) + (s2v + s3);
    float gp = ag[512 + k];                     // includes b_fb
    float gate = 1.f / (1.f + expf(-gp));
    xh[(size_t)b * 3072 + 512 + k] = gate * awe;
    if (kc == 0) {
        bool live = (t < dlens[b]);
        if (tid < NP) out_alpha[((size_t)b * NT + t) * NP + tid] = live ? es[tid] : 0.f;
        const float* er = emb_W + (size_t)caps[sind[b] * NL + t] * ND;
        xh[(size_t)b * 3072 + tid] = er[tid];
        xh[(size_t)b * 3072 + 256 + tid] = er[256 + tid];
    }
}

// ---------------- kC: gates GEMM (grid 32 dchunks x 4 ksplits) + fused cell via finisher ----------------
__global__ __launch_bounds__(256) void k_stepC(
    float* __restrict__ xh, const float* __restrict__ W_ih, const float* __restrict__ W_hh,
    const float* __restrict__ b_ih, const float* __restrict__ b_hh,
    const int* __restrict__ dlens, float* __restrict__ hc, float* __restrict__ hseq,
    float* __restrict__ gpart, int* __restrict__ cnt, int t)
{
    __shared__ float As[1024];        // [32k][32b]
    __shared__ float Ws[64][33];      // [64 gathered rows][32k]
    __shared__ int lastf;
    int dc = blockIdx.x, ks = blockIdx.y, tid = threadIdx.x;
    int lb = tid / 8, lkq = tid % 8;
    int b4 = (tid / 32) * 4, nl = (tid % 32) * 2;
    float acc[4][2] = {};
    for (int kt = ks * 768; kt < ks * 768 + 768; kt += 32) {
        float4 a4 = *reinterpret_cast<const float4*>(xh + (size_t)lb * 3072 + kt + lkq * 4);
        As[(lkq * 4 + 0) * 32 + lb] = a4.x; As[(lkq * 4 + 1) * 32 + lb] = a4.y;
        As[(lkq * 4 + 2) * 32 + lb] = a4.z; As[(lkq * 4 + 3) * 32 + lb] = a4.w;
        #pragma unroll
        for (int r = 0; r < 2; ++r) {
            int s = tid + r * 256;
            int n_l = s / 8, kq = s % 8;
            int q = n_l >> 4, ii = n_l & 15;
            int grow = q * 512 + dc * 16 + ii;
            int kk = kt + kq * 4;
            const float* wrow = (kk < 2560) ? (W_ih + (size_t)grow * 2560 + kk)
                                            : (W_hh + (size_t)grow * 512 + (kk - 2560));
            float4 w4 = *reinterpret_cast<const float4*>(wrow);
            Ws[n_l][kq * 4 + 0] = w4.x; Ws[n_l][kq * 4 + 1] = w4.y;
            Ws[n_l][kq * 4 + 2] = w4.z; Ws[n_l][kq * 4 + 3] = w4.w;
        }
        __syncthreads();
        #pragma unroll
        for (int k = 0; k < 32; ++k) {
            float4 av = *reinterpret_cast<const float4*>(&As[k * 32 + b4]);
            float w0 = Ws[nl][k], w1 = Ws[nl + 1][k];
            acc[0][0] += av.x * w0; acc[0][1] += av.x * w1;
            acc[1][0] += av.y * w0; acc[1][1] += av.y * w1;
            acc[2][0] += av.z * w0; acc[2][1] += av.z * w1;
            acc[3][0] += av.w * w0; acc[3][1] += av.w * w1;
        }
        __syncthreads();
    }
    float* gp = gpart + (size_t)(dc * 4 + ks) * 32 * 64;
    #pragma unroll
    for (int j = 0; j < 2; ++j)
        #pragma unroll
        for (int i = 0; i < 4; ++i)
            gp[(size_t)(b4 + i) * 64 + nl + j] = acc[i][j];
    __threadfence();
    if (tid == 0) lastf = (atomicAdd(&cnt[dc], 1) == 3) ? 1 : 0;
    __syncthreads();
    if (!lastf) return;
    __threadfence();
    // finisher: reduce 4 k-split partials, run LSTM cell for d in [dc*16, dc*16+16)
    for (int idx = tid; idx < 512; idx += 256) {
        int bb = idx >> 4, ii = idx & 15;
        int d = dc * 16 + ii;
        float g[4];
        #pragma unroll
        for (int q = 0; q < 4; ++q) {
            int n = q * 512 + d;
            float s = b_ih[n] + b_hh[n];
            #pragma unroll
            for (int k2 = 0; k2 < 4; ++k2)
                s += gpart[(size_t)(dc * 4 + k2) * 32 * 64 + (size_t)bb * 64 + q * 16 + ii];
            g[q] = s;
        }
        float ig = 1.f / (1.f + expf(-g[0]));
        float fg = 1.f / (1.f + expf(-g[1]));
        float gt = tanhf(g[2]);
        float og = 1.f / (1.f + expf(-g[3]));
        float h_old = hc[(size_t)bb * 1024 + d];
        float c_old = hc[(size_t)bb * 1024 + 512 + d];
        float c_new = fg * c_old + ig * gt;
        float h_new = og * tanhf(c_new);
        hseq[((size_t)t * NB + bb) * ND + d] = h_new;
        bool live = (t < dlens[bb]);
        float hv = live ? h_new : h_old;
        if (live) {
            hc[(size_t)bb * 1024 + d] = h_new;
            hc[(size_t)bb * 1024 + 512 + d] = c_new;
        }
        xh[(size_t)bb * 3072 + 2560 + d] = hv;
    }
    if (tid == 0) __hip_atomic_store(&cnt[dc], 0, __ATOMIC_RELAXED, __HIP_MEMORY_SCOPE_AGENT);
}

// ---------------- launcher ----------------
extern "C" void kernel_launch(void* const* d_in, const int* in_sizes, int n_in,
                              void* d_out, int out_size, void* d_ws, size_t ws_size,
                              hipStream_t stream)
{
    const float* enc   = (const float*)d_in[0];
    const int*   caps  = (const int*)d_in[1];
    const int*   clens = (const int*)d_in[2];
    const float* emb_W = (const float*)d_in[3];
    const float* W_ea  = (const float*)d_in[4];
    const float* b_ea  = (const float*)d_in[5];
    const float* W_da  = (const float*)d_in[6];
    const float* b_da  = (const float*)d_in[7];
    const float* w_fa  = (const float*)d_in[8];
    const float* b_fa  = (const float*)d_in[9];
    const float* W_ih  = (const float*)d_in[10];
    const float* b_ih  = (const float*)d_in[11];
    const float* W_hh  = (const float*)d_in[12];
    const float* b_hh  = (const float*)d_in[13];
    const float* W_h0  = (const float*)d_in[14];
    const float* b_h0  = (const float*)d_in[15];
    const float* W_c0  = (const float*)d_in[16];
    const float* b_c0  = (const float*)d_in[17];
    const float* W_fb  = (const float*)d_in[18];
    const float* b_fb  = (const float*)d_in[19];
    const float* W_fc  = (const float*)d_in[20];
    const float* b_fc  = (const float*)d_in[21];

    float* out = (float*)d_out;
    float* out_alpha = out + (size_t)NB * NT * NV;

    int* iws    = (int*)d_ws;
    int* sind   = iws;
    int* dlens  = iws + 32;
    int* rowmap = iws + 64;
    int* mpad   = iws + 704;
    int* cnt    = iws + 708;
    float* base = (float*)d_ws + 1024;
    float* mean_enc = base;                         // 65536
    float* hc    = mean_enc + NB * NE;              // 32768
    float* attg  = hc + NB * 1024;                  // 81920
    float* xh    = attg + NB * 2560;                // 98304
    float* gpart = xh + NB * 3072;                  // 32*4*32*64 = 262144
    float* hseq  = gpart + 262144;                  // 327680
    float* att1  = hseq + (size_t)NT * NB * ND;     // 3211264

    k_sort<<<1, 64, 0, stream>>>(clens, sind, dlens, rowmap, mpad, cnt);
    k_zero<<<NB * NT, 256, 0, stream>>>(dlens, out);
    k_mean<<<dim3(NE / 256, NB), 256, 0, stream>>>(enc, sind, mean_enc);
    gemm_skinny<<<dim3(16), 256, 0, stream>>>(mean_enc, W_h0, W_c0, b_h0, b_c0, hc, xh);
    gemm_att1<<<dim3(ND / 64, (NB * NP) / 128), 256, 0, stream>>>(enc, W_ea, b_ea, att1, sind);

    for (int t = 0; t < NT; ++t) {
        k_stepA<<<dim3(40), 256, 0, stream>>>(hc, W_da, W_fb, b_da, b_fb, attg);
        k_stepB<<<dim3(8, NB), 256, 0, stream>>>(enc, sind, dlens, caps, emb_W,
                                                 att1, attg, w_fa, b_fa, xh, out_alpha, t);
        k_stepC<<<dim3(32, 4), 256, 0, stream>>>(xh, W_ih, W_hh, b_ih, b_hh,
                                                 dlens, hc, hseq, gpart, cnt, t);
    }

    gemm_preds<<<dim3(10, NV / 128), 256, 0, stream>>>(hseq, W_fc, b_fc, out, rowmap, mpad);
}